// Round 1
// baseline (2224.252 us; speedup 1.0000x reference)
//
#include <hip/hip_runtime.h>
#include <cstdint>
#include <cstddef>

// GRU network: B=16384, T=64, H=32, 3 bidirectional layers + FC(64->2) + tanh.
// Round 0 baseline: wave-synchronous, 8 lanes per (batch, direction) "group",
// each lane owns 4 hidden units. Weights transposed in LDS (conflict-free
// broadcast b128 reads). Inter-layer activations bf16 in d_ws (2 x 128 MiB).

#define BB 16384
#define TT 64
#define HH 32
#define NG 96        // 3*H gate rows
#define GP 100       // padded gate stride for transposed weights (16B aligned, bank-spread)
#define INPAD 68     // padded input-row stride (floats)
#define HPAD 36      // padded h-row stride (floats)
#define GROUPS 32    // groups per block
#define BLOCK 256

__device__ __forceinline__ float sigm(float x) {
    return 1.0f / (1.0f + __expf(-x));
}
__device__ __forceinline__ float tanh_fast(float x) {
    return 2.0f / (1.0f + __expf(-2.0f * x)) - 1.0f;
}
__device__ __forceinline__ unsigned short f2bf(float f) {
    unsigned int u = __float_as_uint(f);
    u = u + 0x7fffu + ((u >> 16) & 1u);   // round-to-nearest-even
    return (unsigned short)(u >> 16);
}

template<int I_IN, bool IS_L0>
__global__ __launch_bounds__(BLOCK, 3)
void gru_layer(const float* __restrict__ x0,              // layer0 input (B,T,2) fp32
               const unsigned short* __restrict__ bin,    // layer>=1 input (B,T,64) bf16 bits
               const float* __restrict__ Wih,             // (2, 96, I_IN)
               const float* __restrict__ Whh,             // (2, 96, 32)
               const float* __restrict__ bih,             // (2, 96)
               const float* __restrict__ bhh,             // (2, 96)
               unsigned short* __restrict__ bout)         // (B,T,64) bf16 bits
{
    __shared__ float sWih[I_IN * GP];          // transposed: [i][gate]
    __shared__ float sWhh[HH * GP];            // transposed: [k][gate]
    __shared__ float sBih[NG];
    __shared__ float sBhh[NG];
    __shared__ float sIn[IS_L0 ? 4 : GROUPS * INPAD];
    __shared__ float sH[GROUPS * HPAD];

    const int tid = threadIdx.x;
    const int grp = tid >> 3;          // 0..31
    const int lane8 = tid & 7;         // 0..7
    const int Gg = blockIdx.x * GROUPS + grp;   // global group id, < 2*B
    const int d = Gg >> 14;            // direction (block-uniform: 512 blocks per dir)
    const int b = Gg & (BB - 1);
    const int j0 = lane8 * 4;          // this lane's hidden-unit tile

    // ---- stage weights transposed into LDS (coalesced global reads) ----
    const float* wih_d = Wih + d * NG * I_IN;
    for (int idx = tid; idx < NG * I_IN; idx += BLOCK) {
        int g = idx / I_IN, i = idx - g * I_IN;
        sWih[i * GP + g] = wih_d[idx];
    }
    const float* whh_d = Whh + d * NG * HH;
    for (int idx = tid; idx < NG * HH; idx += BLOCK) {
        int g = idx / HH, k = idx - g * HH;
        sWhh[k * GP + g] = whh_d[idx];
    }
    if (tid < NG) {
        sBih[tid] = bih[d * NG + tid];
        sBhh[tid] = bhh[d * NG + tid];
    }
    __syncthreads();

    // ---- init h = 0 ----
    #pragma unroll
    for (int q = 0; q < 4; ++q) sH[grp * HPAD + j0 + q] = 0.0f;
    float hown[4] = {0.f, 0.f, 0.f, 0.f};
    __builtin_amdgcn_wave_barrier();

    uint4 nxt;
    if constexpr (!IS_L0) {
        const int t0 = d ? (TT - 1) : 0;
        nxt = *(const uint4*)(bin + ((size_t)b * TT + t0) * 64 + lane8 * 8);
    }

    for (int s = 0; s < TT; ++s) {
        const int t = d ? (TT - 1 - s) : s;

        float accX[3][4], accH[3][4];
        #pragma unroll
        for (int c = 0; c < 3; ++c) {
            float4 bx = *(const float4*)&sBih[c * 32 + j0];
            float4 bh = *(const float4*)&sBhh[c * 32 + j0];
            accX[c][0] = bx.x; accX[c][1] = bx.y; accX[c][2] = bx.z; accX[c][3] = bx.w;
            accH[c][0] = bh.x; accH[c][1] = bh.y; accH[c][2] = bh.z; accH[c][3] = bh.w;
        }

        // ---- input projection ----
        if constexpr (IS_L0) {
            const float* xp = x0 + ((size_t)b * TT + t) * 2;
            float xa = xp[0], xb = xp[1];
            #pragma unroll
            for (int c = 0; c < 3; ++c) {
                float4 w0 = *(const float4*)&sWih[0 * GP + c * 32 + j0];
                float4 w1 = *(const float4*)&sWih[1 * GP + c * 32 + j0];
                accX[c][0] = fmaf(xa, w0.x, fmaf(xb, w1.x, accX[c][0]));
                accX[c][1] = fmaf(xa, w0.y, fmaf(xb, w1.y, accX[c][1]));
                accX[c][2] = fmaf(xa, w0.z, fmaf(xb, w1.z, accX[c][2]));
                accX[c][3] = fmaf(xa, w0.w, fmaf(xb, w1.w, accX[c][3]));
            }
        } else {
            uint4 cur = nxt;
            if (s + 1 < TT) {
                const int tn = d ? (TT - 2 - s) : (s + 1);
                nxt = *(const uint4*)(bin + ((size_t)b * TT + tn) * 64 + lane8 * 8);
            }
            // unpack 8 bf16 -> fp32, stage group's input row in LDS
            float fv[8];
            #pragma unroll
            for (int w = 0; w < 4; ++w) {
                unsigned int uu = ((const unsigned int*)&cur)[w];
                fv[2 * w]     = __uint_as_float(uu << 16);
                fv[2 * w + 1] = __uint_as_float(uu & 0xffff0000u);
            }
            *(float4*)&sIn[grp * INPAD + lane8 * 8]     = make_float4(fv[0], fv[1], fv[2], fv[3]);
            *(float4*)&sIn[grp * INPAD + lane8 * 8 + 4] = make_float4(fv[4], fv[5], fv[6], fv[7]);
            __builtin_amdgcn_wave_barrier();

            #pragma unroll
            for (int i = 0; i < 64; i += 4) {
                float4 xv = *(const float4*)&sIn[grp * INPAD + i];
                const float* xs = (const float*)&xv;
                #pragma unroll
                for (int c = 0; c < 3; ++c) {
                    #pragma unroll
                    for (int di = 0; di < 4; ++di) {
                        float4 wv = *(const float4*)&sWih[(i + di) * GP + c * 32 + j0];
                        accX[c][0] = fmaf(xs[di], wv.x, accX[c][0]);
                        accX[c][1] = fmaf(xs[di], wv.y, accX[c][1]);
                        accX[c][2] = fmaf(xs[di], wv.z, accX[c][2]);
                        accX[c][3] = fmaf(xs[di], wv.w, accX[c][3]);
                    }
                }
            }
        }

        // ---- recurrent projection ----
        #pragma unroll
        for (int k = 0; k < HH; k += 4) {
            float4 hv = *(const float4*)&sH[grp * HPAD + k];
            const float* hs = (const float*)&hv;
            #pragma unroll
            for (int c = 0; c < 3; ++c) {
                #pragma unroll
                for (int di = 0; di < 4; ++di) {
                    float4 wv = *(const float4*)&sWhh[(k + di) * GP + c * 32 + j0];
                    accH[c][0] = fmaf(hs[di], wv.x, accH[c][0]);
                    accH[c][1] = fmaf(hs[di], wv.y, accH[c][1]);
                    accH[c][2] = fmaf(hs[di], wv.z, accH[c][2]);
                    accH[c][3] = fmaf(hs[di], wv.w, accH[c][3]);
                }
            }
        }

        // ---- gates (PyTorch convention: n = tanh(xn + r*(Whh_n h + bhh_n))) ----
        float hnew[4];
        #pragma unroll
        for (int q = 0; q < 4; ++q) {
            float r = sigm(accX[0][q] + accH[0][q]);
            float z = sigm(accX[1][q] + accH[1][q]);
            float n = tanh_fast(accX[2][q] + r * accH[2][q]);
            hnew[q] = n + z * (hown[q] - n);
        }
        __builtin_amdgcn_wave_barrier();
        #pragma unroll
        for (int q = 0; q < 4; ++q) { sH[grp * HPAD + j0 + q] = hnew[q]; hown[q] = hnew[q]; }

        // ---- store h as bf16 into the concat buffer ----
        unsigned int p0 = ((unsigned int)f2bf(hnew[1]) << 16) | (unsigned int)f2bf(hnew[0]);
        unsigned int p1 = ((unsigned int)f2bf(hnew[3]) << 16) | (unsigned int)f2bf(hnew[2]);
        *(uint2*)(bout + ((size_t)b * TT + t) * 64 + d * 32 + j0) = make_uint2(p0, p1);
        __builtin_amdgcn_wave_barrier();
    }
}

__global__ __launch_bounds__(256)
void fc_kernel(const unsigned short* __restrict__ bin,  // (B*T, 64) bf16 bits
               const float* __restrict__ Wfc,           // (2, 64)
               const float* __restrict__ bfc,           // (2,)
               float* __restrict__ out)                 // (B*T, 2) fp32
{
    __shared__ float sw[128];
    __shared__ float sb[2];
    const int tid = threadIdx.x;
    if (tid < 128) sw[tid] = Wfc[tid];
    if (tid < 2) sb[tid] = bfc[tid];
    __syncthreads();

    const size_t u = (size_t)blockIdx.x * 256 + tid;
    const unsigned short* ip = bin + u * 64;
    float a0 = sb[0], a1 = sb[1];
    #pragma unroll
    for (int i = 0; i < 64; i += 8) {
        uint4 raw = *(const uint4*)(ip + i);
        #pragma unroll
        for (int w = 0; w < 4; ++w) {
            unsigned int uu = ((const unsigned int*)&raw)[w];
            float f0 = __uint_as_float(uu << 16);
            float f1 = __uint_as_float(uu & 0xffff0000u);
            a0 = fmaf(f0, sw[i + 2 * w], a0);
            a1 = fmaf(f0, sw[64 + i + 2 * w], a1);
            a0 = fmaf(f1, sw[i + 2 * w + 1], a0);
            a1 = fmaf(f1, sw[64 + i + 2 * w + 1], a1);
        }
    }
    float2 o;
    o.x = tanh_fast(a0);
    o.y = tanh_fast(a1);
    *(float2*)&out[2 * u] = o;
}

extern "C" void kernel_launch(void* const* d_in, const int* in_sizes, int n_in,
                              void* d_out, int out_size, void* d_ws, size_t ws_size,
                              hipStream_t stream)
{
    const float* x    = (const float*)d_in[0];
    const float* Wih0 = (const float*)d_in[1];
    const float* Whh0 = (const float*)d_in[2];
    const float* bih0 = (const float*)d_in[3];
    const float* bhh0 = (const float*)d_in[4];
    const float* WihL = (const float*)d_in[5];   // (2, 2, 96, 64)
    const float* WhhL = (const float*)d_in[6];   // (2, 2, 96, 32)
    const float* bihL = (const float*)d_in[7];   // (2, 2, 96)
    const float* bhhL = (const float*)d_in[8];
    const float* Wfc  = (const float*)d_in[9];
    const float* bfc  = (const float*)d_in[10];

    unsigned short* buf0 = (unsigned short*)d_ws;                    // (B,T,64) bf16
    unsigned short* buf1 = buf0 + (size_t)BB * TT * 64;              // (B,T,64) bf16
    float* out = (float*)d_out;

    const int grid = (2 * BB) / GROUPS;   // 1024 blocks

    gru_layer<2, true><<<grid, BLOCK, 0, stream>>>(
        x, nullptr, Wih0, Whh0, bih0, bhh0, buf0);
    gru_layer<64, false><<<grid, BLOCK, 0, stream>>>(
        nullptr, buf0, WihL, WhhL, bihL, bhhL, buf1);
    gru_layer<64, false><<<grid, BLOCK, 0, stream>>>(
        nullptr, buf1, WihL + 2 * 96 * 64, WhhL + 2 * 96 * 32,
        bihL + 2 * 96, bhhL + 2 * 96, buf0);
    fc_kernel<<<(BB * TT) / 256, 256, 0, stream>>>(buf0, Wfc, bfc, out);
}

// Round 2
// 610.345 us; speedup vs baseline: 3.6443x; 3.6443x over previous
//
#include <hip/hip_runtime.h>
#include <cstdint>
#include <cstddef>

// GRU network B=16384, T=64, H=32, 3 bidir layers + FC(64->2) + tanh.
// R1: MFMA recurrence. One wave owns 16 (b,d) sequences; per step
// 24 input MFMAs (x * [Wih_hi + Wih_lo]) + 18 recurrent MFMAs
// ((h_hi+h_lo) * Whh_hi + h_hi * Whh_lo) in 16x16x32 bf16, fp32 acc.
// hi/lo bf16 splitting gives ~fp32 accuracy; only inter-layer activations
// are single bf16 (same as the passing R0 baseline).

#define BB 16384
#define TT 64

typedef __attribute__((ext_vector_type(8))) short bf16x8;   // 8 bf16, 4 VGPRs
typedef __attribute__((ext_vector_type(4))) float f32x4;    // acc frag

__device__ __forceinline__ float sigm(float x) { return 1.0f / (1.0f + __expf(-x)); }
__device__ __forceinline__ float tanh_fast(float x) { return 2.0f / (1.0f + __expf(-2.0f * x)) - 1.0f; }
__device__ __forceinline__ unsigned short f2bf(float f) {
    unsigned int u = __float_as_uint(f);
    u = u + 0x7fffu + ((u >> 16) & 1u);           // RNE
    return (unsigned short)(u >> 16);
}
__device__ __forceinline__ float bf2f(unsigned short b) {
    return __uint_as_float(((unsigned int)b) << 16);
}
__device__ __forceinline__ f32x4 mfma16(bf16x8 a, bf16x8 b, f32x4 c) {
    return __builtin_amdgcn_mfma_f32_16x16x32_bf16(a, b, c, 0, 0, 0);
}

// A-layout: lane holds A[m = lane&15][k = (lane>>4)*8 + j]
// B-layout: lane holds B[k = (lane>>4)*8 + j][n = lane&15]
// D-layout: lane holds D[row = (lane>>4)*4 + reg][col = lane&15]

template<bool IS_L0>
__global__ __launch_bounds__(256, 2)
void gru_mfma(const float* __restrict__ x0,                // L0 input (B,T,2) fp32
              const unsigned short* __restrict__ bin,      // L>=1 input (B,T,64) bf16
              const float* __restrict__ Wih,               // (2,96,I)  I=2 or 64
              const float* __restrict__ Whh,               // (2,96,32)
              const float* __restrict__ bih,               // (2,96)
              const float* __restrict__ bhh,               // (2,96)
              unsigned short* __restrict__ bout)           // (B,T,64) bf16
{
    constexpr int WST = 72;                   // shorts per Wih row (64 + pad, 144B: 16B-aligned, 2-way max)
    __shared__ __align__(16) short sWhi[IS_L0 ? 8 : 96 * WST];
    __shared__ __align__(16) short sWlo[IS_L0 ? 8 : 96 * WST];
    __shared__ __align__(16) short shH[4][2][16][40];   // [wave][hi/lo][seq][32+pad]

    const int tid  = threadIdx.x;
    const int lane = tid & 63;
    const int wv   = tid >> 6;
    const int d    = blockIdx.x >> 8;                       // direction, block-uniform
    const int b0   = ((int)(blockIdx.x & 255) * 4 + wv) * 16;
    const int col  = lane & 15;
    const int qd   = lane >> 4;

    // ---- stage Wih (hi/lo bf16) into LDS (L>=1) ----
    if constexpr (!IS_L0) {
        const float* wsrc = Wih + d * 96 * 64;
        for (int idx = tid; idx < 96 * 64; idx += 256) {
            int n = idx >> 6, k = idx & 63;
            float w = wsrc[idx];
            unsigned short hi = f2bf(w);
            sWhi[n * WST + k] = (short)hi;
            sWlo[n * WST + k] = (short)f2bf(w - bf2f(hi));
        }
        __syncthreads();
    }

    // ---- Whh fragments (hi/lo) in registers ----
    bf16x8 whhHi[6], whhLo[6];
    {
        const float* wsrc = Whh + d * 96 * 32;
        #pragma unroll
        for (int tl = 0; tl < 6; ++tl) {
            const float* p = wsrc + (tl * 16 + col) * 32 + qd * 8;
            #pragma unroll
            for (int j = 0; j < 8; ++j) {
                float w = p[j];
                unsigned short hi = f2bf(w);
                whhHi[tl][j] = (short)hi;
                whhLo[tl][j] = (short)f2bf(w - bf2f(hi));
            }
        }
    }

    // ---- biases per lane column ----
    float br[2], bz[2], bxn[2], bhn[2];
    #pragma unroll
    for (int tl = 0; tl < 2; ++tl) {
        int g = tl * 16 + col;
        br[tl]  = bih[d * 96 + g]      + bhh[d * 96 + g];
        bz[tl]  = bih[d * 96 + 32 + g] + bhh[d * 96 + 32 + g];
        bxn[tl] = bih[d * 96 + 64 + g];
        bhn[tl] = bhh[d * 96 + 64 + g];
    }

    // ---- L0 input weights (I=2, fp32 exact) ----
    float w0c[6], w1c[6];
    if constexpr (IS_L0) {
        #pragma unroll
        for (int tl = 0; tl < 6; ++tl) {
            w0c[tl] = Wih[d * 96 * 2 + (tl * 16 + col) * 2 + 0];
            w1c[tl] = Wih[d * 96 * 2 + (tl * 16 + col) * 2 + 1];
        }
    }

    const short* wfhBase = sWhi + col * WST + qd * 8;   // lane's B-frag base
    const short* wflBase = sWlo + col * WST + qd * 8;

    bf16x8 hHi = {}, hLo = {};
    float hprev[2][4] = {{0.f,0.f,0.f,0.f},{0.f,0.f,0.f,0.f}};

    // ---- prefetch x for s=0 ----
    uint4 xc0 = {}, xc1 = {};
    float2 xsc[4];
    {
        const int t0 = d ? (TT - 1) : 0;
        if constexpr (IS_L0) {
            #pragma unroll
            for (int q = 0; q < 4; ++q)
                xsc[q] = *(const float2*)(x0 + ((size_t)(b0 + qd * 4 + q) * TT + t0) * 2);
        } else {
            const unsigned short* xr = bin + ((size_t)(b0 + col) * TT + t0) * 64 + qd * 8;
            xc0 = *(const uint4*)xr;
            xc1 = *(const uint4*)(xr + 32);
        }
    }

    for (int s = 0; s < TT; ++s) {
        const int t = d ? (TT - 1 - s) : s;

        // ---- prefetch x for s+1 ----
        uint4 xn0 = xc0, xn1 = xc1;
        float2 xsn[4];
        if (s + 1 < TT) {
            const int tn = d ? (TT - 2 - s) : (s + 1);
            if constexpr (IS_L0) {
                #pragma unroll
                for (int q = 0; q < 4; ++q)
                    xsn[q] = *(const float2*)(x0 + ((size_t)(b0 + qd * 4 + q) * TT + tn) * 2);
            } else {
                const unsigned short* xr = bin + ((size_t)(b0 + col) * TT + tn) * 64 + qd * 8;
                xn0 = *(const uint4*)xr;
                xn1 = *(const uint4*)(xr + 32);
            }
        } else if constexpr (IS_L0) {
            #pragma unroll
            for (int q = 0; q < 4; ++q) xsn[q] = xsc[q];
        }

        // ---- input projection ----
        f32x4 accX[6];
        if constexpr (IS_L0) {
            #pragma unroll
            for (int tl = 0; tl < 6; ++tl)
                #pragma unroll
                for (int q = 0; q < 4; ++q)
                    accX[tl][q] = fmaf(xsc[q].x, w0c[tl], xsc[q].y * w1c[tl]);
        } else {
            bf16x8 a0 = __builtin_bit_cast(bf16x8, xc0);
            bf16x8 a1 = __builtin_bit_cast(bf16x8, xc1);
            #pragma unroll
            for (int tl = 0; tl < 6; ++tl) {
                f32x4 acc = {};
                acc = mfma16(a0, *(const bf16x8*)(wfhBase + tl * 16 * WST), acc);
                acc = mfma16(a1, *(const bf16x8*)(wfhBase + tl * 16 * WST + 32), acc);
                acc = mfma16(a0, *(const bf16x8*)(wflBase + tl * 16 * WST), acc);
                acc = mfma16(a1, *(const bf16x8*)(wflBase + tl * 16 * WST + 32), acc);
                accX[tl] = acc;
            }
        }

        // ---- recurrent projection: (h_hi+h_lo)W_hi + h_hi W_lo ----
        f32x4 accH[6];
        #pragma unroll
        for (int tl = 0; tl < 6; ++tl) {
            f32x4 acc = {};
            acc = mfma16(hHi, whhHi[tl], acc);
            acc = mfma16(hLo, whhHi[tl], acc);
            acc = mfma16(hHi, whhLo[tl], acc);
            accH[tl] = acc;
        }

        // ---- gates + write h (hi/lo) to LDS ----
        #pragma unroll
        for (int tl = 0; tl < 2; ++tl) {
            #pragma unroll
            for (int q = 0; q < 4; ++q) {
                float r = sigm(accX[tl][q] + accH[tl][q] + br[tl]);
                float z = sigm(accX[2 + tl][q] + accH[2 + tl][q] + bz[tl]);
                float n = tanh_fast(accX[4 + tl][q] + bxn[tl] + r * (accH[4 + tl][q] + bhn[tl]));
                float h = n + z * (hprev[tl][q] - n);
                hprev[tl][q] = h;
                unsigned short hi = f2bf(h);
                shH[wv][0][qd * 4 + q][tl * 16 + col] = (short)hi;
                shH[wv][1][qd * 4 + q][tl * 16 + col] = (short)f2bf(h - bf2f(hi));
            }
        }
        __builtin_amdgcn_wave_barrier();

        // ---- D-layout -> A-layout round trip + coalesced output row ----
        {
            const short* hb = &shH[wv][0][0][0];
            const short* lb = &shH[wv][1][0][0];
            hHi = *(const bf16x8*)(hb + col * 40 + qd * 8);
            hLo = *(const bf16x8*)(lb + col * 40 + qd * 8);
            uint4 orow = *(const uint4*)(hb + (lane >> 2) * 40 + (lane & 3) * 8);
            __builtin_amdgcn_wave_barrier();
            *(uint4*)(bout + ((size_t)(b0 + (lane >> 2)) * TT + t) * 64 + d * 32 + (lane & 3) * 8) = orow;
        }

        xc0 = xn0; xc1 = xn1;
        if constexpr (IS_L0) {
            #pragma unroll
            for (int q = 0; q < 4; ++q) xsc[q] = xsn[q];
        }
    }
}

__global__ __launch_bounds__(256)
void fc_kernel(const unsigned short* __restrict__ bin,  // (B*T, 64) bf16
               const float* __restrict__ Wfc,           // (2, 64)
               const float* __restrict__ bfc,           // (2,)
               float* __restrict__ out)                 // (B*T, 2) fp32
{
    __shared__ float sw[128];
    __shared__ float sb[2];
    const int tid = threadIdx.x;
    if (tid < 128) sw[tid] = Wfc[tid];
    if (tid < 2) sb[tid] = bfc[tid];
    __syncthreads();

    const size_t u = (size_t)blockIdx.x * 256 + tid;
    const unsigned short* ip = bin + u * 64;
    float a0 = sb[0], a1 = sb[1];
    #pragma unroll
    for (int i = 0; i < 64; i += 8) {
        uint4 raw = *(const uint4*)(ip + i);
        #pragma unroll
        for (int w = 0; w < 4; ++w) {
            unsigned int uu = ((const unsigned int*)&raw)[w];
            float f0 = __uint_as_float(uu << 16);
            float f1 = __uint_as_float(uu & 0xffff0000u);
            a0 = fmaf(f0, sw[i + 2 * w], a0);
            a1 = fmaf(f0, sw[64 + i + 2 * w], a1);
            a0 = fmaf(f1, sw[i + 2 * w + 1], a0);
            a1 = fmaf(f1, sw[64 + i + 2 * w + 1], a1);
        }
    }
    float2 o;
    o.x = tanh_fast(a0);
    o.y = tanh_fast(a1);
    *(float2*)&out[2 * u] = o;
}

extern "C" void kernel_launch(void* const* d_in, const int* in_sizes, int n_in,
                              void* d_out, int out_size, void* d_ws, size_t ws_size,
                              hipStream_t stream)
{
    const float* x    = (const float*)d_in[0];
    const float* Wih0 = (const float*)d_in[1];
    const float* Whh0 = (const float*)d_in[2];
    const float* bih0 = (const float*)d_in[3];
    const float* bhh0 = (const float*)d_in[4];
    const float* WihL = (const float*)d_in[5];   // (2, 2, 96, 64)
    const float* WhhL = (const float*)d_in[6];   // (2, 2, 96, 32)
    const float* bihL = (const float*)d_in[7];   // (2, 2, 96)
    const float* bhhL = (const float*)d_in[8];
    const float* Wfc  = (const float*)d_in[9];
    const float* bfc  = (const float*)d_in[10];

    unsigned short* buf0 = (unsigned short*)d_ws;           // (B,T,64) bf16
    unsigned short* buf1 = buf0 + (size_t)BB * TT * 64;     // (B,T,64) bf16
    float* out = (float*)d_out;

    gru_mfma<true><<<512, 256, 0, stream>>>(
        x, nullptr, Wih0, Whh0, bih0, bhh0, buf0);
    gru_mfma<false><<<512, 256, 0, stream>>>(
        nullptr, buf0, WihL, WhhL, bihL, bhhL, buf1);
    gru_mfma<false><<<512, 256, 0, stream>>>(
        nullptr, buf1, WihL + 2 * 96 * 64, WhhL + 2 * 96 * 32,
        bihL + 2 * 96, bhhL + 2 * 96, buf0);
    fc_kernel<<<(BB * TT) / 256, 256, 0, stream>>>(buf0, Wfc, bfc, out);
}

// Round 3
// 554.548 us; speedup vs baseline: 4.0109x; 1.1006x over previous
//
#include <hip/hip_runtime.h>
#include <cstdint>
#include <cstddef>

// GRU B=16384 T=64 H=32, 3 bidir layers + FC(64->2) + tanh.
// R2: 2 waves per 16-seq group, split by gate tiles (wave p -> tiles p,p+2,p+4).
// Weights hoisted to VGPR frags (Wih hi-only bf16, Whh hi/lo). h exchanged via
// packed-u32 (lo16|hi16) double-buffered LDS rows, 1 barrier/step, 128-thr blocks.

#define BB 16384
#define TT 64

typedef __attribute__((ext_vector_type(8))) short bf16x8;
typedef __attribute__((ext_vector_type(4))) float f32x4;

__device__ __forceinline__ float sigm(float x) { return 1.0f / (1.0f + __expf(-x)); }
__device__ __forceinline__ float tanh_fast(float x) { return 2.0f / (1.0f + __expf(-2.0f * x)) - 1.0f; }
__device__ __forceinline__ unsigned short f2bf(float f) {
    unsigned int u = __float_as_uint(f);
    u = u + 0x7fffu + ((u >> 16) & 1u);
    return (unsigned short)(u >> 16);
}
__device__ __forceinline__ float bf2f(unsigned short b) {
    return __uint_as_float(((unsigned int)b) << 16);
}
__device__ __forceinline__ f32x4 mfma16(bf16x8 a, bf16x8 b, f32x4 c) {
    return __builtin_amdgcn_mfma_f32_16x16x32_bf16(a, b, c, 0, 0, 0);
}

// A: lane = A[m=lane&15][k=(lane>>4)*8+j]   B: lane = B[k=(lane>>4)*8+j][n=lane&15]
// D: lane = D[row=(lane>>4)*4+reg][col=lane&15]

#define HST 36   // words per h row (32 units + pad; 16B-aligned reads)

template<bool IS_L0>
__global__ __launch_bounds__(128, 4)
void gru_mfma(const float* __restrict__ x0,
              const unsigned short* __restrict__ bin,
              const float* __restrict__ Wih,               // (2,96,I)
              const float* __restrict__ Whh,               // (2,96,32)
              const float* __restrict__ bih,               // (2,96)
              const float* __restrict__ bhh,               // (2,96)
              unsigned short* __restrict__ bout)           // (B,T,64) bf16
{
    __shared__ unsigned int hbuf[2][16 * HST];   // packed (lo16<<16)|hi16 per unit

    const int tid  = threadIdx.x;
    const int lane = tid & 63;
    const int p    = tid >> 6;                    // wave in pair: 0 or 1
    const int d    = blockIdx.x >> 10;
    const int b0   = (int)(blockIdx.x & 1023) * 16;
    const int col  = lane & 15;
    const int qd   = lane >> 4;
    const int u    = p * 16 + col;                // this lane's owned h-unit

    // ---- hoist weight fragments to VGPRs ----
    bf16x8 whhHi[3], whhLo[3];
    {
        const float* wsrc = Whh + d * 96 * 32;
        #pragma unroll
        for (int tl = 0; tl < 3; ++tl) {
            const int g = (p + 2 * tl) * 16 + col;
            const float* pr = wsrc + g * 32 + qd * 8;
            #pragma unroll
            for (int j = 0; j < 8; ++j) {
                float w = pr[j];
                unsigned short hi = f2bf(w);
                whhHi[tl][j] = (short)hi;
                whhLo[tl][j] = (short)f2bf(w - bf2f(hi));
            }
        }
    }
    bf16x8 wihF[3][2];
    float w0c[3], w1c[3];
    if constexpr (!IS_L0) {
        const float* wsrc = Wih + d * 96 * 64;
        #pragma unroll
        for (int tl = 0; tl < 3; ++tl) {
            const int g = (p + 2 * tl) * 16 + col;
            #pragma unroll
            for (int kc = 0; kc < 2; ++kc) {
                const float* pr = wsrc + g * 64 + kc * 32 + qd * 8;
                #pragma unroll
                for (int j = 0; j < 8; ++j) wihF[tl][kc][j] = (short)f2bf(pr[j]);
            }
        }
    } else {
        #pragma unroll
        for (int tl = 0; tl < 3; ++tl) {
            const int g = (p + 2 * tl) * 16 + col;
            w0c[tl] = Wih[d * 96 * 2 + g * 2 + 0];
            w1c[tl] = Wih[d * 96 * 2 + g * 2 + 1];
        }
    }

    // ---- per-lane gate biases (unit u) ----
    const float br  = bih[d * 96 + u]      + bhh[d * 96 + u];
    const float bz  = bih[d * 96 + 32 + u] + bhh[d * 96 + 32 + u];
    const float bxn = bih[d * 96 + 64 + u];
    const float bhn = bhh[d * 96 + 64 + u];

    const int t0 = d ? (TT - 1) : 0;
    const int dt = d ? -1 : 1;

    // ---- input pointers (incremental) ----
    const unsigned short* xptr = nullptr;
    const float* xfp = nullptr;
    uint4 xc0 = {}, xc1 = {};
    float2 xsc[4];
    if constexpr (!IS_L0) {
        xptr = bin + ((size_t)(b0 + col) * TT + t0) * 64 + qd * 8;
        xc0 = *(const uint4*)xptr;
        xc1 = *(const uint4*)(xptr + 32);
    } else {
        xfp = x0 + ((size_t)(b0 + qd * 4) * TT + t0) * 2;
        #pragma unroll
        for (int q = 0; q < 4; ++q) xsc[q] = *(const float2*)(xfp + q * TT * 2);
    }

    // ---- output pointer (incremental): lane stores seq p*8+(lane>>3), units (lane&7)*4 ----
    unsigned short* optr = bout + ((size_t)(b0 + p * 8 + (lane >> 3)) * TT + t0) * 64
                         + d * 32 + (lane & 7) * 4;

    bf16x8 hHi = {}, hLo = {};
    float hprev[4] = {0.f, 0.f, 0.f, 0.f};

    for (int s = 0; s < TT; ++s) {
        // ---- prefetch next x ----
        uint4 xn0 = xc0, xn1 = xc1;
        float2 xsn[4];
        if (s + 1 < TT) {
            if constexpr (!IS_L0) {
                xptr += dt * 64;
                xn0 = *(const uint4*)xptr;
                xn1 = *(const uint4*)(xptr + 32);
            } else {
                xfp += dt * 2;
                #pragma unroll
                for (int q = 0; q < 4; ++q) xsn[q] = *(const float2*)(xfp + q * TT * 2);
            }
        } else if constexpr (IS_L0) {
            #pragma unroll
            for (int q = 0; q < 4; ++q) xsn[q] = xsc[q];
        }

        // ---- input projection into acc (r,z) and accXN (n kept separate) ----
        f32x4 accR = {}, accZ = {}, accXN = {};
        if constexpr (!IS_L0) {
            bf16x8 a0 = __builtin_bit_cast(bf16x8, xc0);
            bf16x8 a1 = __builtin_bit_cast(bf16x8, xc1);
            accR  = mfma16(a0, wihF[0][0], accR);  accR  = mfma16(a1, wihF[0][1], accR);
            accZ  = mfma16(a0, wihF[1][0], accZ);  accZ  = mfma16(a1, wihF[1][1], accZ);
            accXN = mfma16(a0, wihF[2][0], accXN); accXN = mfma16(a1, wihF[2][1], accXN);
        } else {
            #pragma unroll
            for (int q = 0; q < 4; ++q) {
                accR[q]  = fmaf(xsc[q].x, w0c[0], xsc[q].y * w1c[0]);
                accZ[q]  = fmaf(xsc[q].x, w0c[1], xsc[q].y * w1c[1]);
                accXN[q] = fmaf(xsc[q].x, w0c[2], xsc[q].y * w1c[2]);
            }
        }

        // ---- recurrence: (hHi+hLo)*Whi + hHi*Wlo ----
        accR = mfma16(hHi, whhHi[0], accR);
        accR = mfma16(hLo, whhHi[0], accR);
        accR = mfma16(hHi, whhLo[0], accR);
        accZ = mfma16(hHi, whhHi[1], accZ);
        accZ = mfma16(hLo, whhHi[1], accZ);
        accZ = mfma16(hHi, whhLo[1], accZ);
        f32x4 accHN = {};
        accHN = mfma16(hHi, whhHi[2], accHN);
        accHN = mfma16(hLo, whhHi[2], accHN);
        accHN = mfma16(hHi, whhLo[2], accHN);

        // ---- gates + pack (lo16<<16)|hi16 and write LDS ----
        unsigned int* hb = &hbuf[s & 1][0];
        #pragma unroll
        for (int q = 0; q < 4; ++q) {
            float r = sigm(accR[q] + br);
            float z = sigm(accZ[q] + bz);
            float n = tanh_fast(accXN[q] + bxn + r * (accHN[q] + bhn));
            float h = n + z * (hprev[q] - n);
            hprev[q] = h;
            unsigned int uu = __float_as_uint(h);
            unsigned int u2 = uu + 0x7fffu + ((uu >> 16) & 1u);
            float lo_f = h - __uint_as_float(u2 & 0xffff0000u);
            unsigned int U = (__float_as_uint(lo_f) & 0xffff0000u) | (u2 >> 16);
            hb[(qd * 4 + q) * HST + u] = U;
        }
        __syncthreads();

        // ---- rebuild A-frags (hi/lo) from packed rows ----
        {
            const unsigned int* rp = hb + col * HST + qd * 8;
            uint4 w0 = *(const uint4*)rp;
            uint4 w1 = *(const uint4*)(rp + 4);
            unsigned int hh[4], ll[4];
            const unsigned int* wsrc0 = (const unsigned int*)&w0;
            const unsigned int* wsrc1 = (const unsigned int*)&w1;
            #pragma unroll
            for (int j = 0; j < 2; ++j) {
                hh[j]     = (wsrc0[2 * j + 1] << 16) | (wsrc0[2 * j] & 0xffffu);
                ll[j]     = (wsrc0[2 * j + 1] & 0xffff0000u) | (wsrc0[2 * j] >> 16);
                hh[2 + j] = (wsrc1[2 * j + 1] << 16) | (wsrc1[2 * j] & 0xffffu);
                ll[2 + j] = (wsrc1[2 * j + 1] & 0xffff0000u) | (wsrc1[2 * j] >> 16);
            }
            hHi = __builtin_bit_cast(bf16x8, *(uint4*)hh);
            hLo = __builtin_bit_cast(bf16x8, *(uint4*)ll);
        }

        // ---- coalesced output row (bf16 hi) ----
        {
            const unsigned int* rp = hb + (p * 8 + (lane >> 3)) * HST + (lane & 7) * 4;
            uint4 v = *(const uint4*)rp;
            uint2 o;
            o.x = (v.y << 16) | (v.x & 0xffffu);
            o.y = (v.w << 16) | (v.z & 0xffffu);
            *(uint2*)optr = o;
            optr += dt * 64;
        }

        xc0 = xn0; xc1 = xn1;
        if constexpr (IS_L0) {
            #pragma unroll
            for (int q = 0; q < 4; ++q) xsc[q] = xsn[q];
        }
    }
}

__global__ __launch_bounds__(256)
void fc_kernel(const unsigned short* __restrict__ bin,
               const float* __restrict__ Wfc,
               const float* __restrict__ bfc,
               float* __restrict__ out)
{
    __shared__ float sw[128];
    __shared__ float sb[2];
    const int tid = threadIdx.x;
    if (tid < 128) sw[tid] = Wfc[tid];
    if (tid < 2) sb[tid] = bfc[tid];
    __syncthreads();

    const size_t uidx = (size_t)blockIdx.x * 256 + tid;
    const unsigned short* ip = bin + uidx * 64;
    float a0 = sb[0], a1 = sb[1];
    #pragma unroll
    for (int i = 0; i < 64; i += 8) {
        uint4 raw = *(const uint4*)(ip + i);
        #pragma unroll
        for (int w = 0; w < 4; ++w) {
            unsigned int uu = ((const unsigned int*)&raw)[w];
            float f0 = __uint_as_float(uu << 16);
            float f1 = __uint_as_float(uu & 0xffff0000u);
            a0 = fmaf(f0, sw[i + 2 * w], a0);
            a1 = fmaf(f0, sw[64 + i + 2 * w], a1);
            a0 = fmaf(f1, sw[i + 2 * w + 1], a0);
            a1 = fmaf(f1, sw[64 + i + 2 * w + 1], a1);
        }
    }
    float2 o;
    o.x = tanh_fast(a0);
    o.y = tanh_fast(a1);
    *(float2*)&out[2 * uidx] = o;
}

extern "C" void kernel_launch(void* const* d_in, const int* in_sizes, int n_in,
                              void* d_out, int out_size, void* d_ws, size_t ws_size,
                              hipStream_t stream)
{
    const float* x    = (const float*)d_in[0];
    const float* Wih0 = (const float*)d_in[1];
    const float* Whh0 = (const float*)d_in[2];
    const float* bih0 = (const float*)d_in[3];
    const float* bhh0 = (const float*)d_in[4];
    const float* WihL = (const float*)d_in[5];
    const float* WhhL = (const float*)d_in[6];
    const float* bihL = (const float*)d_in[7];
    const float* bhhL = (const float*)d_in[8];
    const float* Wfc  = (const float*)d_in[9];
    const float* bfc  = (const float*)d_in[10];

    unsigned short* buf0 = (unsigned short*)d_ws;
    unsigned short* buf1 = buf0 + (size_t)BB * TT * 64;
    float* out = (float*)d_out;

    gru_mfma<true><<<2048, 128, 0, stream>>>(
        x, nullptr, Wih0, Whh0, bih0, bhh0, buf0);
    gru_mfma<false><<<2048, 128, 0, stream>>>(
        nullptr, buf0, WihL, WhhL, bihL, bhhL, buf1);
    gru_mfma<false><<<2048, 128, 0, stream>>>(
        nullptr, buf1, WihL + 2 * 96 * 64, WhhL + 2 * 96 * 32,
        bihL + 2 * 96, bhhL + 2 * 96, buf0);
    fc_kernel<<<(BB * TT) / 256, 256, 0, stream>>>(buf0, Wfc, bfc, out);
}

// Round 4
// 520.613 us; speedup vs baseline: 4.2724x; 1.0652x over previous
//
#include <hip/hip_runtime.h>
#include <cstdint>
#include <cstddef>

// GRU B=16384 T=64 H=32, 3 bidir layers + FC(64->2) + tanh.
// R3: A=W (m=gate), B=h^T (n=seq) -> D[gate][seq]. One wave owns 16 seqs x all
// 96 gates; h exchange is wave-private LDS (no __syncthreads, no bit-shuffle:
// bf16 shorts stored in B-frag order). Biases enter as MFMA C operand.
// Whh hi/lo + h hi/lo (fp32-ish recurrence), Wih hi-only, output bf16.

#define BB 16384
#define TT 64

typedef __attribute__((ext_vector_type(8))) short bf16x8;
typedef __attribute__((ext_vector_type(4))) float f32x4;

__device__ __forceinline__ float sigm(float x) { return 1.0f / (1.0f + __expf(-x)); }
__device__ __forceinline__ float tanh_fast(float x) { return 2.0f / (1.0f + __expf(-2.0f * x)) - 1.0f; }
__device__ __forceinline__ unsigned short f2bf(float f) {
    unsigned int u = __float_as_uint(f);
    u = u + 0x7fffu + ((u >> 16) & 1u);
    return (unsigned short)(u >> 16);
}
__device__ __forceinline__ float bf2f(unsigned short b) {
    return __uint_as_float(((unsigned int)b) << 16);
}
__device__ __forceinline__ f32x4 mfma16(bf16x8 a, bf16x8 b, f32x4 c) {
    return __builtin_amdgcn_mfma_f32_16x16x32_bf16(a, b, c, 0, 0, 0);
}

// A: lane = A[m=lane&15][k=(lane>>4)*8+j]   B: lane = B[k=(lane>>4)*8+j][n=lane&15]
// D: lane = D[row=(lane>>4)*4+reg][col=lane&15]
// Here: A = weight tile (m=gate row), B = h^T / x^T (n=seq), D = gates[gate][seq].

#define HROW 40   // shorts per h row (32 units + 8 pad); 80 B, 16B-aligned rows

template<bool IS_L0>
__global__ __launch_bounds__(256, 2)
void gru_mfma(const float* __restrict__ x0,
              const unsigned short* __restrict__ bin,
              const float* __restrict__ Wih,               // (2,96,I)
              const float* __restrict__ Whh,               // (2,96,32)
              const float* __restrict__ bih,               // (2,96)
              const float* __restrict__ bhh,               // (2,96)
              unsigned short* __restrict__ bout)           // (B,T,64) bf16
{
    __shared__ __align__(16) short sHi[4][16 * HROW];
    __shared__ __align__(16) short sLo[4][16 * HROW];

    const int tid  = threadIdx.x;
    const int lane = tid & 63;
    const int wv   = tid >> 6;
    const int g    = blockIdx.x * 4 + wv;        // 0..2047
    const int d    = g >> 10;
    const int b0   = (g & 1023) * 16;
    const int col  = lane & 15;
    const int qd   = lane >> 4;

    // ---- Whh A-frags (hi/lo), 6 gate tiles ----
    bf16x8 whhHi[6], whhLo[6];
    {
        const float* wsrc = Whh + d * 96 * 32;
        #pragma unroll
        for (int t = 0; t < 6; ++t) {
            const float* pr = wsrc + (t * 16 + col) * 32 + qd * 8;
            #pragma unroll
            for (int j = 0; j < 8; ++j) {
                float w = pr[j];
                unsigned short hi = f2bf(w);
                whhHi[t][j] = (short)hi;
                whhLo[t][j] = (short)f2bf(w - bf2f(hi));
            }
        }
    }

    // ---- Wih A-frags (hi only) or L0 scalar weights ----
    bf16x8 wihF[6][2];
    float w0c[6][4], w1c[6][4];
    if constexpr (!IS_L0) {
        const float* wsrc = Wih + d * 96 * 64;
        #pragma unroll
        for (int t = 0; t < 6; ++t)
            #pragma unroll
            for (int kc = 0; kc < 2; ++kc) {
                const float* pr = wsrc + (t * 16 + col) * 64 + kc * 32 + qd * 8;
                #pragma unroll
                for (int j = 0; j < 8; ++j) wihF[t][kc][j] = (short)f2bf(pr[j]);
            }
    } else {
        #pragma unroll
        for (int t = 0; t < 6; ++t)
            #pragma unroll
            for (int q = 0; q < 4; ++q) {
                const float* pr = Wih + d * 96 * 2 + (t * 16 + qd * 4 + q) * 2;
                w0c[t][q] = pr[0];
                w1c[t][q] = pr[1];
            }
    }

    // ---- biases as MFMA C-operand frags (gate = t*16 + qd*4 + q) ----
    f32x4 biasIn[6], biasHN[2];
    {
        const float* bi = bih + d * 96;
        const float* bh = bhh + d * 96;
        #pragma unroll
        for (int t = 0; t < 4; ++t) {
            float4 a = *(const float4*)(bi + t * 16 + qd * 4);
            float4 b = *(const float4*)(bh + t * 16 + qd * 4);
            biasIn[t][0] = a.x + b.x; biasIn[t][1] = a.y + b.y;
            biasIn[t][2] = a.z + b.z; biasIn[t][3] = a.w + b.w;
        }
        #pragma unroll
        for (int i = 0; i < 2; ++i) {
            float4 a = *(const float4*)(bi + 64 + i * 16 + qd * 4);
            float4 b = *(const float4*)(bh + 64 + i * 16 + qd * 4);
            biasIn[4 + i][0] = a.x; biasIn[4 + i][1] = a.y;
            biasIn[4 + i][2] = a.z; biasIn[4 + i][3] = a.w;
            biasHN[i][0] = b.x; biasHN[i][1] = b.y;
            biasHN[i][2] = b.z; biasHN[i][3] = b.w;
        }
    }

    const int t0 = d ? (TT - 1) : 0;
    const int dt = d ? -1 : 1;

    // ---- input pointers (incremental); x as B-frags ----
    const unsigned short* xptr = nullptr;
    const float* xfp = nullptr;
    uint4 xc0 = {}, xc1 = {};
    float2 xsc = {};
    if constexpr (!IS_L0) {
        xptr = bin + ((size_t)(b0 + col) * TT + t0) * 64 + qd * 8;
        xc0 = *(const uint4*)xptr;
        xc1 = *(const uint4*)(xptr + 32);
    } else {
        xfp = x0 + ((size_t)(b0 + col) * TT + t0) * 2;
        xsc = *(const float2*)xfp;
    }

    // ---- output pointer: lane stores seq lane>>2, units (lane&3)*8..+7 ----
    unsigned short* optr = bout + ((size_t)(b0 + (lane >> 2)) * TT + t0) * 64
                         + d * 32 + (lane & 3) * 8;

    short* hb = &sHi[wv][0];
    short* lb = &sLo[wv][0];

    bf16x8 hHi = {}, hLo = {};
    float hprev[2][4] = {{0.f,0.f,0.f,0.f},{0.f,0.f,0.f,0.f}};

    for (int s = 0; s < TT; ++s) {
        // ---- prefetch next x ----
        uint4 xn0 = xc0, xn1 = xc1;
        float2 xsn = xsc;
        if (s + 1 < TT) {
            if constexpr (!IS_L0) {
                xptr += dt * 64;
                xn0 = *(const uint4*)xptr;
                xn1 = *(const uint4*)(xptr + 32);
            } else {
                xfp += dt * 2;
                xsn = *(const float2*)xfp;
            }
        }

        // ---- input projection (bias rides in as C) ----
        f32x4 acc[6];
        if constexpr (!IS_L0) {
            bf16x8 a0 = __builtin_bit_cast(bf16x8, xc0);
            bf16x8 a1 = __builtin_bit_cast(bf16x8, xc1);
            #pragma unroll
            for (int t = 0; t < 6; ++t) {
                acc[t] = mfma16(wihF[t][0], a0, biasIn[t]);
                acc[t] = mfma16(wihF[t][1], a1, acc[t]);
            }
        } else {
            #pragma unroll
            for (int t = 0; t < 6; ++t)
                #pragma unroll
                for (int q = 0; q < 4; ++q)
                    acc[t][q] = fmaf(xsc.x, w0c[t][q], fmaf(xsc.y, w1c[t][q], biasIn[t][q]));
        }

        // ---- recurrence: W_hi*(hHi+hLo) + W_lo*hHi ----
        #pragma unroll
        for (int t = 0; t < 4; ++t) {
            acc[t] = mfma16(whhHi[t], hHi, acc[t]);
            acc[t] = mfma16(whhHi[t], hLo, acc[t]);
            acc[t] = mfma16(whhLo[t], hHi, acc[t]);
        }
        f32x4 accHN[2];
        #pragma unroll
        for (int i = 0; i < 2; ++i) {
            accHN[i] = mfma16(whhHi[4 + i], hHi, biasHN[i]);
            accHN[i] = mfma16(whhHi[4 + i], hLo, accHN[i]);
            accHN[i] = mfma16(whhLo[4 + i], hHi, accHN[i]);
        }

        // ---- gates; write h (hi RNE, lo trunc) straight into B-frag order ----
        #pragma unroll
        for (int i = 0; i < 2; ++i) {
            unsigned int hw[2], lw[2];
            #pragma unroll
            for (int q = 0; q < 4; ++q) {
                float r = sigm(acc[i][q]);
                float z = sigm(acc[2 + i][q]);
                float n = tanh_fast(acc[4 + i][q] + r * accHN[i][q]);
                float h = n + z * (hprev[i][q] - n);
                hprev[i][q] = h;
                unsigned int uu = __float_as_uint(h);
                unsigned int uh = (uu + 0x7fffu + ((uu >> 16) & 1u)) >> 16;
                float lof = h - __uint_as_float(uh << 16);
                unsigned int ul = __float_as_uint(lof) >> 16;
                if (q & 1) { hw[q >> 1] |= uh << 16; lw[q >> 1] |= ul << 16; }
                else       { hw[q >> 1]  = uh;       lw[q >> 1]  = ul;       }
            }
            *(uint2*)(hb + col * HROW + i * 16 + qd * 4) = make_uint2(hw[0], hw[1]);
            *(uint2*)(lb + col * HROW + i * 16 + qd * 4) = make_uint2(lw[0], lw[1]);
        }
        __builtin_amdgcn_wave_barrier();

        // ---- rebuild B-frags + coalesced output row (wave-private, no barrier) ----
        hHi = *(const bf16x8*)(hb + col * HROW + qd * 8);
        hLo = *(const bf16x8*)(lb + col * HROW + qd * 8);
        uint4 orow = *(const uint4*)(hb + (lane >> 2) * HROW + (lane & 3) * 8);
        __builtin_amdgcn_wave_barrier();
        *(uint4*)optr = orow;
        optr += dt * 64;

        xc0 = xn0; xc1 = xn1; xsc = xsn;
    }
}

__global__ __launch_bounds__(256)
void fc_kernel(const unsigned short* __restrict__ bin,
               const float* __restrict__ Wfc,
               const float* __restrict__ bfc,
               float* __restrict__ out)
{
    __shared__ float sw[128];
    __shared__ float sb[2];
    const int tid = threadIdx.x;
    if (tid < 128) sw[tid] = Wfc[tid];
    if (tid < 2) sb[tid] = bfc[tid];
    __syncthreads();

    const size_t uidx = (size_t)blockIdx.x * 256 + tid;
    const unsigned short* ip = bin + uidx * 64;
    float a0 = sb[0], a1 = sb[1];
    #pragma unroll
    for (int i = 0; i < 64; i += 8) {
        uint4 raw = *(const uint4*)(ip + i);
        #pragma unroll
        for (int w = 0; w < 4; ++w) {
            unsigned int uu = ((const unsigned int*)&raw)[w];
            float f0 = __uint_as_float(uu << 16);
            float f1 = __uint_as_float(uu & 0xffff0000u);
            a0 = fmaf(f0, sw[i + 2 * w], a0);
            a1 = fmaf(f0, sw[64 + i + 2 * w], a1);
            a0 = fmaf(f1, sw[i + 2 * w + 1], a0);
            a1 = fmaf(f1, sw[64 + i + 2 * w + 1], a1);
        }
    }
    float2 o;
    o.x = tanh_fast(a0);
    o.y = tanh_fast(a1);
    *(float2*)&out[2 * uidx] = o;
}

extern "C" void kernel_launch(void* const* d_in, const int* in_sizes, int n_in,
                              void* d_out, int out_size, void* d_ws, size_t ws_size,
                              hipStream_t stream)
{
    const float* x    = (const float*)d_in[0];
    const float* Wih0 = (const float*)d_in[1];
    const float* Whh0 = (const float*)d_in[2];
    const float* bih0 = (const float*)d_in[3];
    const float* bhh0 = (const float*)d_in[4];
    const float* WihL = (const float*)d_in[5];
    const float* WhhL = (const float*)d_in[6];
    const float* bihL = (const float*)d_in[7];
    const float* bhhL = (const float*)d_in[8];
    const float* Wfc  = (const float*)d_in[9];
    const float* bfc  = (const float*)d_in[10];

    unsigned short* buf0 = (unsigned short*)d_ws;
    unsigned short* buf1 = buf0 + (size_t)BB * TT * 64;
    float* out = (float*)d_out;

    gru_mfma<true><<<512, 256, 0, stream>>>(
        x, nullptr, Wih0, Whh0, bih0, bhh0, buf0);
    gru_mfma<false><<<512, 256, 0, stream>>>(
        nullptr, buf0, WihL, WhhL, bihL, bhhL, buf1);
    gru_mfma<false><<<512, 256, 0, stream>>>(
        nullptr, buf1, WihL + 2 * 96 * 64, WhhL + 2 * 96 * 32,
        bihL + 2 * 96, bhhL + 2 * 96, buf0);
    fc_kernel<<<(BB * TT) / 256, 256, 0, stream>>>(buf0, Wfc, bfc, out);
}

// Round 5
// 505.750 us; speedup vs baseline: 4.3979x; 1.0294x over previous
//
#include <hip/hip_runtime.h>
#include <cstdint>
#include <cstddef>

// GRU B=16384 T=64 H=32, 3 bidir layers + FC(64->2) + tanh.
// R4: gate-row permutation makes D-frag == next-step B-frag. Within each
// 32-row gate block, row position p = T*16 + qd*4 + q holds original unit
// 8*qd + 4*T + q. Each lane's 8 gate outputs (T=0,1; q=0..3) pack directly
// into its h B-fragment (units qd*8..qd*8+7, natural order) -- zero LDS,
// zero barriers, h never leaves registers. Whh hi/lo + h hi/lo recurrence,
// Wih hi-only, biases ride in as MFMA C operand, output bf16 stored direct.

#define BB 16384
#define TT 64

typedef __attribute__((ext_vector_type(8))) short bf16x8;
typedef __attribute__((ext_vector_type(4))) float f32x4;

__device__ __forceinline__ float sigm(float x) { return 1.0f / (1.0f + __expf(-x)); }
__device__ __forceinline__ float tanh_fast(float x) { return 2.0f / (1.0f + __expf(-2.0f * x)) - 1.0f; }
__device__ __forceinline__ unsigned short f2bf(float f) {
    unsigned int u = __float_as_uint(f);
    u = u + 0x7fffu + ((u >> 16) & 1u);
    return (unsigned short)(u >> 16);
}
__device__ __forceinline__ float bf2f(unsigned short b) {
    return __uint_as_float(((unsigned int)b) << 16);
}
__device__ __forceinline__ f32x4 mfma16(bf16x8 a, bf16x8 b, f32x4 c) {
    return __builtin_amdgcn_mfma_f32_16x16x32_bf16(a, b, c, 0, 0, 0);
}
// RNE-round pair (a,b) -> packed bf16x2 word; also emit truncated lo residuals.
__device__ __forceinline__ void pk_pair(float a, float b,
                                        unsigned int& w, unsigned int& l) {
    unsigned int ua = __float_as_uint(a), ub = __float_as_uint(b);
    unsigned int ha = (ua + 0x7fffu + ((ua >> 16) & 1u)) >> 16;
    unsigned int hb = (ub + 0x7fffu + ((ub >> 16) & 1u)) >> 16;
    w = ha | (hb << 16);
    float la = a - __uint_as_float(ha << 16);
    float lb = b - __uint_as_float(hb << 16);
    l = (__float_as_uint(la) >> 16) | (__float_as_uint(lb) & 0xffff0000u);
}

// A: lane = A[m=lane&15][k=(lane>>4)*8+j]   B: lane = B[k=(lane>>4)*8+j][n=lane&15]
// D: lane = D[row=(lane>>4)*4+reg][col=lane&15]
// Permutation: gate-block row position (T*16 + qd*4 + q) <- original unit 8qd+4T+q.

template<bool IS_L0>
__global__ __launch_bounds__(256, 2)
void gru_mfma(const float* __restrict__ x0,
              const unsigned short* __restrict__ bin,
              const float* __restrict__ Wih,               // (2,96,I)
              const float* __restrict__ Whh,               // (2,96,32)
              const float* __restrict__ bih,               // (2,96)
              const float* __restrict__ bhh,               // (2,96)
              unsigned short* __restrict__ bout)           // (B,T,64) bf16
{
    const int tid  = threadIdx.x;
    const int lane = tid & 63;
    const int wv   = tid >> 6;
    const int g    = blockIdx.x * 4 + wv;        // 0..2047
    const int d    = g >> 10;
    const int b0   = (g & 1023) * 16;
    const int col  = lane & 15;
    const int qd   = lane >> 4;

    // ---- Whh A-frags (hi/lo), 6 tiles, permuted rows ----
    bf16x8 whhHi[6], whhLo[6];
    {
        const float* wsrc = Whh + d * 96 * 32;
        #pragma unroll
        for (int t = 0; t < 6; ++t) {
            const int row = (t >> 1) * 32 + 8 * (col >> 2) + 4 * (t & 1) + (col & 3);
            const float* pr = wsrc + row * 32 + qd * 8;
            #pragma unroll
            for (int j = 0; j < 8; ++j) {
                float w = pr[j];
                unsigned short hi = f2bf(w);
                whhHi[t][j] = (short)hi;
                whhLo[t][j] = (short)f2bf(w - bf2f(hi));
            }
        }
    }

    // ---- Wih A-frags (hi only, permuted rows) or L0 scalar weights ----
    bf16x8 wihF[6][2];
    float w0c[6][4], w1c[6][4];
    if constexpr (!IS_L0) {
        const float* wsrc = Wih + d * 96 * 64;
        #pragma unroll
        for (int t = 0; t < 6; ++t) {
            const int row = (t >> 1) * 32 + 8 * (col >> 2) + 4 * (t & 1) + (col & 3);
            #pragma unroll
            for (int kc = 0; kc < 2; ++kc) {
                const float* pr = wsrc + row * 64 + kc * 32 + qd * 8;
                #pragma unroll
                for (int j = 0; j < 8; ++j) wihF[t][kc][j] = (short)f2bf(pr[j]);
            }
        }
    } else {
        #pragma unroll
        for (int t = 0; t < 6; ++t)
            #pragma unroll
            for (int q = 0; q < 4; ++q) {
                const int row = (t >> 1) * 32 + 8 * qd + 4 * (t & 1) + q;
                const float* pr = Wih + d * 96 * 2 + row * 2;
                w0c[t][q] = pr[0];
                w1c[t][q] = pr[1];
            }
    }

    // ---- biases as C-operand frags; D entry (qd,q) of tile t = row 8qd+4T+q ----
    f32x4 biasIn[6], biasHN[2];
    {
        const float* bi = bih + d * 96;
        const float* bh = bhh + d * 96;
        #pragma unroll
        for (int t = 0; t < 4; ++t) {
            const int off = (t >> 1) * 32 + 8 * qd + 4 * (t & 1);
            float4 a = *(const float4*)(bi + off);
            float4 b = *(const float4*)(bh + off);
            biasIn[t][0] = a.x + b.x; biasIn[t][1] = a.y + b.y;
            biasIn[t][2] = a.z + b.z; biasIn[t][3] = a.w + b.w;
        }
        #pragma unroll
        for (int T = 0; T < 2; ++T) {
            const int off = 64 + 8 * qd + 4 * T;
            float4 a = *(const float4*)(bi + off);
            float4 b = *(const float4*)(bh + off);
            biasIn[4 + T][0] = a.x; biasIn[4 + T][1] = a.y;
            biasIn[4 + T][2] = a.z; biasIn[4 + T][3] = a.w;
            biasHN[T][0] = b.x; biasHN[T][1] = b.y;
            biasHN[T][2] = b.z; biasHN[T][3] = b.w;
        }
    }

    const int t0 = d ? (TT - 1) : 0;
    const int dt = d ? -1 : 1;

    // ---- input pointers (incremental); x as B-frags ----
    const unsigned short* xptr = nullptr;
    const float* xfp = nullptr;
    uint4 xc0 = {}, xc1 = {};
    float2 xsc = {};
    if constexpr (!IS_L0) {
        xptr = bin + ((size_t)(b0 + col) * TT + t0) * 64 + qd * 8;
        xc0 = *(const uint4*)xptr;
        xc1 = *(const uint4*)(xptr + 32);
    } else {
        xfp = x0 + ((size_t)(b0 + col) * TT + t0) * 2;
        xsc = *(const float2*)xfp;
    }

    // ---- output pointer: lane stores seq=col, units qd*8..qd*8+7 (16B) ----
    unsigned short* optr = bout + ((size_t)(b0 + col) * TT + t0) * 64 + d * 32 + qd * 8;

    bf16x8 hHi = {}, hLo = {};
    float hprev[2][4] = {{0.f,0.f,0.f,0.f},{0.f,0.f,0.f,0.f}};

    for (int s = 0; s < TT; ++s) {
        // ---- prefetch next x ----
        uint4 xn0 = xc0, xn1 = xc1;
        float2 xsn = xsc;
        if (s + 1 < TT) {
            if constexpr (!IS_L0) {
                xptr += dt * 64;
                xn0 = *(const uint4*)xptr;
                xn1 = *(const uint4*)(xptr + 32);
            } else {
                xfp += dt * 2;
                xsn = *(const float2*)xfp;
            }
        }

        // ---- input projection (bias rides in as C) ----
        f32x4 acc[6];
        if constexpr (!IS_L0) {
            bf16x8 a0 = __builtin_bit_cast(bf16x8, xc0);
            bf16x8 a1 = __builtin_bit_cast(bf16x8, xc1);
            #pragma unroll
            for (int t = 0; t < 6; ++t) {
                acc[t] = mfma16(wihF[t][0], a0, biasIn[t]);
                acc[t] = mfma16(wihF[t][1], a1, acc[t]);
            }
        } else {
            #pragma unroll
            for (int t = 0; t < 6; ++t)
                #pragma unroll
                for (int q = 0; q < 4; ++q)
                    acc[t][q] = fmaf(xsc.x, w0c[t][q], fmaf(xsc.y, w1c[t][q], biasIn[t][q]));
        }

        // ---- recurrence: W_hi*(hHi+hLo) + W_lo*hHi ----
        #pragma unroll
        for (int t = 0; t < 4; ++t) {
            acc[t] = mfma16(whhHi[t], hHi, acc[t]);
            acc[t] = mfma16(whhHi[t], hLo, acc[t]);
            acc[t] = mfma16(whhLo[t], hHi, acc[t]);
        }
        f32x4 accHN[2];
        #pragma unroll
        for (int T = 0; T < 2; ++T) {
            accHN[T] = mfma16(whhHi[4 + T], hHi, biasHN[T]);
            accHN[T] = mfma16(whhHi[4 + T], hLo, accHN[T]);
            accHN[T] = mfma16(whhLo[4 + T], hHi, accHN[T]);
        }

        // ---- gates; pack straight into next-step B-frags (in registers) ----
        unsigned int hw[4], lw[4];
        #pragma unroll
        for (int T = 0; T < 2; ++T) {
            float hv[4];
            #pragma unroll
            for (int q = 0; q < 4; ++q) {
                float r = sigm(acc[T][q]);
                float z = sigm(acc[2 + T][q]);
                float n = tanh_fast(acc[4 + T][q] + r * accHN[T][q]);
                float h = n + z * (hprev[T][q] - n);
                hprev[T][q] = h;
                hv[q] = h;
            }
            pk_pair(hv[0], hv[1], hw[2 * T],     lw[2 * T]);
            pk_pair(hv[2], hv[3], hw[2 * T + 1], lw[2 * T + 1]);
        }
        hHi = __builtin_bit_cast(bf16x8, *(uint4*)hw);
        hLo = __builtin_bit_cast(bf16x8, *(uint4*)lw);

        // ---- direct global store of h (bf16 hi), natural unit order ----
        *(uint4*)optr = *(uint4*)hw;
        optr += dt * 64;

        xc0 = xn0; xc1 = xn1; xsc = xsn;
    }
}

__global__ __launch_bounds__(256)
void fc_kernel(const unsigned short* __restrict__ bin,
               const float* __restrict__ Wfc,
               const float* __restrict__ bfc,
               float* __restrict__ out)
{
    __shared__ float sw[128];
    __shared__ float sb[2];
    const int tid = threadIdx.x;
    if (tid < 128) sw[tid] = Wfc[tid];
    if (tid < 2) sb[tid] = bfc[tid];
    __syncthreads();

    const size_t uidx = (size_t)blockIdx.x * 256 + tid;
    const unsigned short* ip = bin + uidx * 64;
    float a0 = sb[0], a1 = sb[1];
    #pragma unroll
    for (int i = 0; i < 64; i += 8) {
        uint4 raw = *(const uint4*)(ip + i);
        #pragma unroll
        for (int w = 0; w < 4; ++w) {
            unsigned int uu = ((const unsigned int*)&raw)[w];
            float f0 = __uint_as_float(uu << 16);
            float f1 = __uint_as_float(uu & 0xffff0000u);
            a0 = fmaf(f0, sw[i + 2 * w], a0);
            a1 = fmaf(f0, sw[64 + i + 2 * w], a1);
            a0 = fmaf(f1, sw[i + 2 * w + 1], a0);
            a1 = fmaf(f1, sw[64 + i + 2 * w + 1], a1);
        }
    }
    float2 o;
    o.x = tanh_fast(a0);
    o.y = tanh_fast(a1);
    *(float2*)&out[2 * uidx] = o;
}

extern "C" void kernel_launch(void* const* d_in, const int* in_sizes, int n_in,
                              void* d_out, int out_size, void* d_ws, size_t ws_size,
                              hipStream_t stream)
{
    const float* x    = (const float*)d_in[0];
    const float* Wih0 = (const float*)d_in[1];
    const float* Whh0 = (const float*)d_in[2];
    const float* bih0 = (const float*)d_in[3];
    const float* bhh0 = (const float*)d_in[4];
    const float* WihL = (const float*)d_in[5];
    const float* WhhL = (const float*)d_in[6];
    const float* bihL = (const float*)d_in[7];
    const float* bhhL = (const float*)d_in[8];
    const float* Wfc  = (const float*)d_in[9];
    const float* bfc  = (const float*)d_in[10];

    unsigned short* buf0 = (unsigned short*)d_ws;
    unsigned short* buf1 = buf0 + (size_t)BB * TT * 64;
    float* out = (float*)d_out;

    gru_mfma<true><<<512, 256, 0, stream>>>(
        x, nullptr, Wih0, Whh0, bih0, bhh0, buf0);
    gru_mfma<false><<<512, 256, 0, stream>>>(
        nullptr, buf0, WihL, WhhL, bihL, bhhL, buf1);
    gru_mfma<false><<<512, 256, 0, stream>>>(
        nullptr, buf1, WihL + 2 * 96 * 64, WhhL + 2 * 96 * 32,
        bihL + 2 * 96, bhhL + 2 * 96, buf0);
    fc_kernel<<<(BB * TT) / 256, 256, 0, stream>>>(buf0, Wfc, bfc, out);
}

// Round 6
// 392.711 us; speedup vs baseline: 5.6638x; 1.2878x over previous
//
#include <hip/hip_runtime.h>
#include <cstdint>
#include <cstddef>

// GRU B=16384 T=64 H=32, 3 bidir layers + FC(64->2) + tanh.
// R5: gate-VALU diet on the R4 structure (permuted gate rows, D-frag==B-frag,
// zero LDS). exp2-folded weights (no arg muls before v_exp), pairwise-shared
// v_rcp (3->1.5 per update), v_cvt_pk_bf16_f32 packing, s-loop unrolled x2
// (A/B reg sets, zero per-step index math). Whh hi/lo + h hi/lo recurrence.

#define BB 16384
#define TT 64

typedef __attribute__((ext_vector_type(8))) short bf16x8;
typedef __attribute__((ext_vector_type(4))) float f32x4;

#if __has_builtin(__builtin_amdgcn_exp2f)
#define EXP2(x) __builtin_amdgcn_exp2f(x)
#else
#define EXP2(x) exp2f(x)
#endif
#if __has_builtin(__builtin_amdgcn_rcpf)
#define RCP(x) __builtin_amdgcn_rcpf(x)
#else
#define RCP(x) (1.0f / (x))
#endif

#define SR (-1.4426950408889634f)   // -log2(e)   for r,z gates
#define SN (-2.8853900817779268f)   // -2*log2(e) for n gate

__device__ __forceinline__ float tanh_fast(float x) { return 2.0f / (1.0f + __expf(-2.0f * x)) - 1.0f; }
__device__ __forceinline__ unsigned short f2bf(float f) {
    unsigned int u = __float_as_uint(f);
    u = u + 0x7fffu + ((u >> 16) & 1u);
    return (unsigned short)(u >> 16);
}
__device__ __forceinline__ float bf2f(unsigned short b) {
    return __uint_as_float(((unsigned int)b) << 16);
}
__device__ __forceinline__ unsigned int cvt_pk(float a, float b) {
#if __has_builtin(__builtin_amdgcn_cvt_pk_bf16_f32)
    typedef __bf16 bf16x2_t __attribute__((ext_vector_type(2)));
    bf16x2_t p = __builtin_amdgcn_cvt_pk_bf16_f32(a, b);
    return __builtin_bit_cast(unsigned int, p);
#else
    unsigned int ua = __float_as_uint(a), ub = __float_as_uint(b);
    unsigned int ha = (ua + 0x7fffu + ((ua >> 16) & 1u)) >> 16;
    unsigned int hb = (ub + 0x7fffu + ((ub >> 16) & 1u)) & 0xffff0000u;
    return ha | hb;
#endif
}
__device__ __forceinline__ f32x4 mfma16(bf16x8 a, bf16x8 b, f32x4 c) {
    return __builtin_amdgcn_mfma_f32_16x16x32_bf16(a, b, c, 0, 0, 0);
}

// Gates for a q-pair. Inputs are exp2-prescaled preactivations (C carried bias).
// sigma(x) = rcp(1+exp2(SR*x)); tanh(v) = 2*rcp(1+exp2(SN*v)) - 1.
__device__ __forceinline__ void gate_pair(float aR0, float aR1, float aZ0, float aZ1,
                                          float xN0, float xN1, float hN0, float hN1,
                                          float& hp0, float& hp1) {
    float er0 = EXP2(aR0), er1 = EXP2(aR1);
    float ez0 = EXP2(aZ0), ez1 = EXP2(aZ1);
    float Ar0 = 1.f + er0, Ar1 = 1.f + er1;
    float Az0 = 1.f + ez0, Az1 = 1.f + ez1;
    float iR = RCP(Ar0 * Ar1);
    float iZ = RCP(Az0 * Az1);
    float r0 = iR * Ar1, r1 = iR * Ar0;
    float z0 = iZ * Az1, z1 = iZ * Az0;
    float v0 = fmaf(r0, hN0, xN0), v1 = fmaf(r1, hN1, xN1);
    float en0 = EXP2(v0), en1 = EXP2(v1);
    float An0 = 1.f + en0, An1 = 1.f + en1;
    float iN = RCP(An0 * An1);
    float n0 = fmaf(2.f, iN * An1, -1.f);
    float n1 = fmaf(2.f, iN * An0, -1.f);
    hp0 = fmaf(z0, hp0 - n0, n0);
    hp1 = fmaf(z1, hp1 - n1, n1);
}

// A: lane = A[m=lane&15][k=(lane>>4)*8+j]   B: lane = B[k=(lane>>4)*8+j][n=lane&15]
// D: lane = D[row=(lane>>4)*4+reg][col=lane&15]
// Gate-row permutation: block row position (T*16 + qd*4 + q) <- original unit 8qd+4T+q.

template<bool IS_L0>
__global__ __launch_bounds__(256, 2)
void gru_mfma(const float* __restrict__ x0,
              const unsigned short* __restrict__ bin,
              const float* __restrict__ Wih,               // (2,96,I)
              const float* __restrict__ Whh,               // (2,96,32)
              const float* __restrict__ bih,               // (2,96)
              const float* __restrict__ bhh,               // (2,96)
              unsigned short* __restrict__ bout)           // (B,T,64) bf16
{
    const int tid  = threadIdx.x;
    const int lane = tid & 63;
    const int wv   = tid >> 6;
    const int g    = blockIdx.x * 4 + wv;        // 0..2047
    const int d    = g >> 10;
    const int b0   = (g & 1023) * 16;
    const int col  = lane & 15;
    const int qd   = lane >> 4;

    // ---- Whh A-frags (hi/lo), permuted rows, exp2-prescaled ----
    bf16x8 whhHi[6], whhLo[6];
    {
        const float* wsrc = Whh + d * 96 * 32;
        #pragma unroll
        for (int t = 0; t < 6; ++t) {
            const float sc = (t < 4) ? SR : SN;
            const int row = (t >> 1) * 32 + 8 * (col >> 2) + 4 * (t & 1) + (col & 3);
            const float* pr = wsrc + row * 32 + qd * 8;
            #pragma unroll
            for (int j = 0; j < 8; ++j) {
                float w = pr[j] * sc;
                unsigned short hi = f2bf(w);
                whhHi[t][j] = (short)hi;
                whhLo[t][j] = (short)f2bf(w - bf2f(hi));
            }
        }
    }

    // ---- Wih A-frags (hi only, permuted, prescaled) or L0 scalar weights ----
    bf16x8 wihF[6][2];
    float w0c[6][4], w1c[6][4];
    if constexpr (!IS_L0) {
        const float* wsrc = Wih + d * 96 * 64;
        #pragma unroll
        for (int t = 0; t < 6; ++t) {
            const float sc = (t < 4) ? SR : SN;
            const int row = (t >> 1) * 32 + 8 * (col >> 2) + 4 * (t & 1) + (col & 3);
            #pragma unroll
            for (int kc = 0; kc < 2; ++kc) {
                const float* pr = wsrc + row * 64 + kc * 32 + qd * 8;
                #pragma unroll
                for (int j = 0; j < 8; ++j) wihF[t][kc][j] = (short)f2bf(pr[j] * sc);
            }
        }
    } else {
        #pragma unroll
        for (int t = 0; t < 6; ++t) {
            const float sc = (t < 4) ? SR : SN;
            #pragma unroll
            for (int q = 0; q < 4; ++q) {
                const int row = (t >> 1) * 32 + 8 * qd + 4 * (t & 1) + q;
                const float* pr = Wih + d * 96 * 2 + row * 2;
                w0c[t][q] = pr[0] * sc;
                w1c[t][q] = pr[1] * sc;
            }
        }
    }

    // ---- biases as C-operand frags (prescaled) ----
    f32x4 biasIn[6], biasHN[2];
    {
        const float* bi = bih + d * 96;
        const float* bh = bhh + d * 96;
        #pragma unroll
        for (int t = 0; t < 4; ++t) {
            const int off = (t >> 1) * 32 + 8 * qd + 4 * (t & 1);
            float4 a = *(const float4*)(bi + off);
            float4 b = *(const float4*)(bh + off);
            biasIn[t][0] = (a.x + b.x) * SR; biasIn[t][1] = (a.y + b.y) * SR;
            biasIn[t][2] = (a.z + b.z) * SR; biasIn[t][3] = (a.w + b.w) * SR;
        }
        #pragma unroll
        for (int T = 0; T < 2; ++T) {
            const int off = 64 + 8 * qd + 4 * T;
            float4 a = *(const float4*)(bi + off);
            float4 b = *(const float4*)(bh + off);
            biasIn[4 + T][0] = a.x * SN; biasIn[4 + T][1] = a.y * SN;
            biasIn[4 + T][2] = a.z * SN; biasIn[4 + T][3] = a.w * SN;
            biasHN[T][0] = b.x * SN; biasHN[T][1] = b.y * SN;
            biasHN[T][2] = b.z * SN; biasHN[T][3] = b.w * SN;
        }
    }

    const int t0 = d ? (TT - 1) : 0;
    const int dt = d ? -1 : 1;

    bf16x8 hHi = {}, hLo = {};
    float hprev[2][4] = {{0.f,0.f,0.f,0.f},{0.f,0.f,0.f,0.f}};

    // ---- one full GRU step (x regs in, h state updated, store h row) ----
    auto STEP = [&](uint4 xa, uint4 xb, float2 xs, unsigned short* outp) {
        f32x4 acc[6];
        if constexpr (!IS_L0) {
            bf16x8 a0 = __builtin_bit_cast(bf16x8, xa);
            bf16x8 a1 = __builtin_bit_cast(bf16x8, xb);
            #pragma unroll
            for (int t = 0; t < 6; ++t) {
                acc[t] = mfma16(wihF[t][0], a0, biasIn[t]);
                acc[t] = mfma16(wihF[t][1], a1, acc[t]);
            }
        } else {
            #pragma unroll
            for (int t = 0; t < 6; ++t)
                #pragma unroll
                for (int q = 0; q < 4; ++q)
                    acc[t][q] = fmaf(xs.x, w0c[t][q], fmaf(xs.y, w1c[t][q], biasIn[t][q]));
        }

        #pragma unroll
        for (int t = 0; t < 4; ++t) {
            acc[t] = mfma16(whhHi[t], hHi, acc[t]);
            acc[t] = mfma16(whhHi[t], hLo, acc[t]);
            acc[t] = mfma16(whhLo[t], hHi, acc[t]);
        }
        f32x4 accHN[2];
        #pragma unroll
        for (int T = 0; T < 2; ++T) {
            accHN[T] = mfma16(whhHi[4 + T], hHi, biasHN[T]);
            accHN[T] = mfma16(whhHi[4 + T], hLo, accHN[T]);
            accHN[T] = mfma16(whhLo[4 + T], hHi, accHN[T]);
        }

        unsigned int hw[4], lw[4];
        #pragma unroll
        for (int T = 0; T < 2; ++T) {
            float h0 = hprev[T][0], h1 = hprev[T][1];
            float h2 = hprev[T][2], h3 = hprev[T][3];
            gate_pair(acc[T][0], acc[T][1], acc[2 + T][0], acc[2 + T][1],
                      acc[4 + T][0], acc[4 + T][1], accHN[T][0], accHN[T][1], h0, h1);
            gate_pair(acc[T][2], acc[T][3], acc[2 + T][2], acc[2 + T][3],
                      acc[4 + T][2], acc[4 + T][3], accHN[T][2], accHN[T][3], h2, h3);
            hprev[T][0] = h0; hprev[T][1] = h1; hprev[T][2] = h2; hprev[T][3] = h3;
            unsigned int w01 = cvt_pk(h0, h1);
            unsigned int w23 = cvt_pk(h2, h3);
            float g0 = __uint_as_float(w01 << 16), g1 = __uint_as_float(w01 & 0xffff0000u);
            float g2 = __uint_as_float(w23 << 16), g3 = __uint_as_float(w23 & 0xffff0000u);
            hw[2 * T]     = w01;
            hw[2 * T + 1] = w23;
            lw[2 * T]     = cvt_pk(h0 - g0, h1 - g1);
            lw[2 * T + 1] = cvt_pk(h2 - g2, h3 - g3);
        }
        hHi = __builtin_bit_cast(bf16x8, *(uint4*)hw);
        hLo = __builtin_bit_cast(bf16x8, *(uint4*)lw);
        *(uint4*)outp = *(uint4*)hw;
    };

    // ---- pointers: A = even steps, B = odd steps ----
    const unsigned short* xptrA = nullptr; const unsigned short* xptrB = nullptr;
    const float* xfpA = nullptr; const float* xfpB = nullptr;
    uint4 xA0 = {}, xA1 = {}, xB0 = {}, xB1 = {};
    float2 xsA = {}, xsB = {};
    if constexpr (!IS_L0) {
        xptrA = bin + ((size_t)(b0 + col) * TT + t0) * 64 + qd * 8;
        xptrB = xptrA + dt * 64;
        xA0 = *(const uint4*)xptrA; xA1 = *(const uint4*)(xptrA + 32);
        xB0 = *(const uint4*)xptrB; xB1 = *(const uint4*)(xptrB + 32);
    } else {
        xfpA = x0 + ((size_t)(b0 + col) * TT + t0) * 2;
        xfpB = xfpA + dt * 2;
        xsA = *(const float2*)xfpA;
        xsB = *(const float2*)xfpB;
    }
    unsigned short* optrA = bout + ((size_t)(b0 + col) * TT + t0) * 64 + d * 32 + qd * 8;
    unsigned short* optrB = optrA + dt * 64;

    for (int k = 0; k < 31; ++k) {            // steps 0..61, prefetch 2..63
        STEP(xA0, xA1, xsA, optrA); optrA += dt * 128;
        if constexpr (!IS_L0) {
            xptrA += dt * 128;
            xA0 = *(const uint4*)xptrA; xA1 = *(const uint4*)(xptrA + 32);
        } else {
            xfpA += dt * 4; xsA = *(const float2*)xfpA;
        }
        STEP(xB0, xB1, xsB, optrB); optrB += dt * 128;
        if constexpr (!IS_L0) {
            xptrB += dt * 128;
            xB0 = *(const uint4*)xptrB; xB1 = *(const uint4*)(xptrB + 32);
        } else {
            xfpB += dt * 4; xsB = *(const float2*)xfpB;
        }
    }
    STEP(xA0, xA1, xsA, optrA);               // s = 62
    STEP(xB0, xB1, xsB, optrB);               // s = 63
}

__global__ __launch_bounds__(256)
void fc_kernel(const unsigned short* __restrict__ bin,
               const float* __restrict__ Wfc,
               const float* __restrict__ bfc,
               float* __restrict__ out)
{
    __shared__ float sw[128];
    __shared__ float sb[2];
    const int tid = threadIdx.x;
    if (tid < 128) sw[tid] = Wfc[tid];
    if (tid < 2) sb[tid] = bfc[tid];
    __syncthreads();

    const size_t uidx = (size_t)blockIdx.x * 256 + tid;
    const unsigned short* ip = bin + uidx * 64;
    float a0 = sb[0], a1 = sb[1];
    #pragma unroll
    for (int i = 0; i < 64; i += 8) {
        uint4 raw = *(const uint4*)(ip + i);
        #pragma unroll
        for (int w = 0; w < 4; ++w) {
            unsigned int uu = ((const unsigned int*)&raw)[w];
            float f0 = __uint_as_float(uu << 16);
            float f1 = __uint_as_float(uu & 0xffff0000u);
            a0 = fmaf(f0, sw[i + 2 * w], a0);
            a1 = fmaf(f0, sw[64 + i + 2 * w], a1);
            a0 = fmaf(f1, sw[i + 2 * w + 1], a0);
            a1 = fmaf(f1, sw[64 + i + 2 * w + 1], a1);
        }
    }
    float2 o;
    o.x = tanh_fast(a0);
    o.y = tanh_fast(a1);
    *(float2*)&out[2 * uidx] = o;
}

extern "C" void kernel_launch(void* const* d_in, const int* in_sizes, int n_in,
                              void* d_out, int out_size, void* d_ws, size_t ws_size,
                              hipStream_t stream)
{
    const float* x    = (const float*)d_in[0];
    const float* Wih0 = (const float*)d_in[1];
    const float* Whh0 = (const float*)d_in[2];
    const float* bih0 = (const float*)d_in[3];
    const float* bhh0 = (const float*)d_in[4];
    const float* WihL = (const float*)d_in[5];
    const float* WhhL = (const float*)d_in[6];
    const float* bihL = (const float*)d_in[7];
    const float* bhhL = (const float*)d_in[8];
    const float* Wfc  = (const float*)d_in[9];
    const float* bfc  = (const float*)d_in[10];

    unsigned short* buf0 = (unsigned short*)d_ws;
    unsigned short* buf1 = buf0 + (size_t)BB * TT * 64;
    float* out = (float*)d_out;

    gru_mfma<true><<<512, 256, 0, stream>>>(
        x, nullptr, Wih0, Whh0, bih0, bhh0, buf0);
    gru_mfma<false><<<512, 256, 0, stream>>>(
        nullptr, buf0, WihL, WhhL, bihL, bhhL, buf1);
    gru_mfma<false><<<512, 256, 0, stream>>>(
        nullptr, buf1, WihL + 2 * 96 * 64, WhhL + 2 * 96 * 32,
        bihL + 2 * 96, bhhL + 2 * 96, buf0);
    fc_kernel<<<(BB * TT) / 256, 256, 0, stream>>>(buf0, Wfc, bfc, out);
}

// Round 7
// 373.884 us; speedup vs baseline: 5.9490x; 1.0504x over previous
//
#include <hip/hip_runtime.h>
#include <cstdint>
#include <cstddef>

// GRU B=16384 T=64 H=32, 3 bidir layers + FC(64->2) + tanh.
// R6: R5 structure (permuted gate rows, D-frag==B-frag, zero LDS, exp2-folded
// weights, shared rcp, cvt_pk packing, 2x unroll) with the hLo residual
// dropped from the recurrence: rec = (whhHi + whhLo) * hHi (12 MFMAs, chain 2).
// W stays fp32-precise (hi+lo bf16); h enters MFMA as plain bf16; fp32 hprev
// still carries the exact blend state across steps.

#define BB 16384
#define TT 64

typedef __attribute__((ext_vector_type(8))) short bf16x8;
typedef __attribute__((ext_vector_type(4))) float f32x4;

#if __has_builtin(__builtin_amdgcn_exp2f)
#define EXP2(x) __builtin_amdgcn_exp2f(x)
#else
#define EXP2(x) exp2f(x)
#endif
#if __has_builtin(__builtin_amdgcn_rcpf)
#define RCP(x) __builtin_amdgcn_rcpf(x)
#else
#define RCP(x) (1.0f / (x))
#endif

#define SR (-1.4426950408889634f)   // -log2(e)   for r,z gates
#define SN (-2.8853900817779268f)   // -2*log2(e) for n gate

__device__ __forceinline__ float tanh_fast(float x) { return 2.0f / (1.0f + __expf(-2.0f * x)) - 1.0f; }
__device__ __forceinline__ unsigned short f2bf(float f) {
    unsigned int u = __float_as_uint(f);
    u = u + 0x7fffu + ((u >> 16) & 1u);
    return (unsigned short)(u >> 16);
}
__device__ __forceinline__ float bf2f(unsigned short b) {
    return __uint_as_float(((unsigned int)b) << 16);
}
__device__ __forceinline__ unsigned int cvt_pk(float a, float b) {
#if __has_builtin(__builtin_amdgcn_cvt_pk_bf16_f32)
    typedef __bf16 bf16x2_t __attribute__((ext_vector_type(2)));
    bf16x2_t p = __builtin_amdgcn_cvt_pk_bf16_f32(a, b);
    return __builtin_bit_cast(unsigned int, p);
#else
    unsigned int ua = __float_as_uint(a), ub = __float_as_uint(b);
    unsigned int ha = (ua + 0x7fffu + ((ua >> 16) & 1u)) >> 16;
    unsigned int hb = (ub + 0x7fffu + ((ub >> 16) & 1u)) & 0xffff0000u;
    return ha | hb;
#endif
}
__device__ __forceinline__ f32x4 mfma16(bf16x8 a, bf16x8 b, f32x4 c) {
    return __builtin_amdgcn_mfma_f32_16x16x32_bf16(a, b, c, 0, 0, 0);
}

// Gates for a q-pair. Inputs are exp2-prescaled preactivations (C carried bias).
// sigma(x) = rcp(1+exp2(SR*x)); tanh(v) = 2*rcp(1+exp2(SN*v)) - 1.
__device__ __forceinline__ void gate_pair(float aR0, float aR1, float aZ0, float aZ1,
                                          float xN0, float xN1, float hN0, float hN1,
                                          float& hp0, float& hp1) {
    float er0 = EXP2(aR0), er1 = EXP2(aR1);
    float ez0 = EXP2(aZ0), ez1 = EXP2(aZ1);
    float Ar0 = 1.f + er0, Ar1 = 1.f + er1;
    float Az0 = 1.f + ez0, Az1 = 1.f + ez1;
    float iR = RCP(Ar0 * Ar1);
    float iZ = RCP(Az0 * Az1);
    float r0 = iR * Ar1, r1 = iR * Ar0;
    float z0 = iZ * Az1, z1 = iZ * Az0;
    float v0 = fmaf(r0, hN0, xN0), v1 = fmaf(r1, hN1, xN1);
    float en0 = EXP2(v0), en1 = EXP2(v1);
    float An0 = 1.f + en0, An1 = 1.f + en1;
    float iN = RCP(An0 * An1);
    float n0 = fmaf(2.f, iN * An1, -1.f);
    float n1 = fmaf(2.f, iN * An0, -1.f);
    hp0 = fmaf(z0, hp0 - n0, n0);
    hp1 = fmaf(z1, hp1 - n1, n1);
}

// A: lane = A[m=lane&15][k=(lane>>4)*8+j]   B: lane = B[k=(lane>>4)*8+j][n=lane&15]
// D: lane = D[row=(lane>>4)*4+reg][col=lane&15]
// Gate-row permutation: block row position (T*16 + qd*4 + q) <- original unit 8qd+4T+q.

template<bool IS_L0>
__global__ __launch_bounds__(256, 2)
void gru_mfma(const float* __restrict__ x0,
              const unsigned short* __restrict__ bin,
              const float* __restrict__ Wih,               // (2,96,I)
              const float* __restrict__ Whh,               // (2,96,32)
              const float* __restrict__ bih,               // (2,96)
              const float* __restrict__ bhh,               // (2,96)
              unsigned short* __restrict__ bout)           // (B,T,64) bf16
{
    const int tid  = threadIdx.x;
    const int lane = tid & 63;
    const int wv   = tid >> 6;
    const int g    = blockIdx.x * 4 + wv;        // 0..2047
    const int d    = g >> 10;
    const int b0   = (g & 1023) * 16;
    const int col  = lane & 15;
    const int qd   = lane >> 4;

    // ---- Whh A-frags (hi/lo), permuted rows, exp2-prescaled ----
    bf16x8 whhHi[6], whhLo[6];
    {
        const float* wsrc = Whh + d * 96 * 32;
        #pragma unroll
        for (int t = 0; t < 6; ++t) {
            const float sc = (t < 4) ? SR : SN;
            const int row = (t >> 1) * 32 + 8 * (col >> 2) + 4 * (t & 1) + (col & 3);
            const float* pr = wsrc + row * 32 + qd * 8;
            #pragma unroll
            for (int j = 0; j < 8; ++j) {
                float w = pr[j] * sc;
                unsigned short hi = f2bf(w);
                whhHi[t][j] = (short)hi;
                whhLo[t][j] = (short)f2bf(w - bf2f(hi));
            }
        }
    }

    // ---- Wih A-frags (hi only, permuted, prescaled) or L0 scalar weights ----
    bf16x8 wihF[6][2];
    float w0c[6][4], w1c[6][4];
    if constexpr (!IS_L0) {
        const float* wsrc = Wih + d * 96 * 64;
        #pragma unroll
        for (int t = 0; t < 6; ++t) {
            const float sc = (t < 4) ? SR : SN;
            const int row = (t >> 1) * 32 + 8 * (col >> 2) + 4 * (t & 1) + (col & 3);
            #pragma unroll
            for (int kc = 0; kc < 2; ++kc) {
                const float* pr = wsrc + row * 64 + kc * 32 + qd * 8;
                #pragma unroll
                for (int j = 0; j < 8; ++j) wihF[t][kc][j] = (short)f2bf(pr[j] * sc);
            }
        }
    } else {
        #pragma unroll
        for (int t = 0; t < 6; ++t) {
            const float sc = (t < 4) ? SR : SN;
            #pragma unroll
            for (int q = 0; q < 4; ++q) {
                const int row = (t >> 1) * 32 + 8 * qd + 4 * (t & 1) + q;
                const float* pr = Wih + d * 96 * 2 + row * 2;
                w0c[t][q] = pr[0] * sc;
                w1c[t][q] = pr[1] * sc;
            }
        }
    }

    // ---- biases as C-operand frags (prescaled) ----
    f32x4 biasIn[6], biasHN[2];
    {
        const float* bi = bih + d * 96;
        const float* bh = bhh + d * 96;
        #pragma unroll
        for (int t = 0; t < 4; ++t) {
            const int off = (t >> 1) * 32 + 8 * qd + 4 * (t & 1);
            float4 a = *(const float4*)(bi + off);
            float4 b = *(const float4*)(bh + off);
            biasIn[t][0] = (a.x + b.x) * SR; biasIn[t][1] = (a.y + b.y) * SR;
            biasIn[t][2] = (a.z + b.z) * SR; biasIn[t][3] = (a.w + b.w) * SR;
        }
        #pragma unroll
        for (int T = 0; T < 2; ++T) {
            const int off = 64 + 8 * qd + 4 * T;
            float4 a = *(const float4*)(bi + off);
            float4 b = *(const float4*)(bh + off);
            biasIn[4 + T][0] = a.x * SN; biasIn[4 + T][1] = a.y * SN;
            biasIn[4 + T][2] = a.z * SN; biasIn[4 + T][3] = a.w * SN;
            biasHN[T][0] = b.x * SN; biasHN[T][1] = b.y * SN;
            biasHN[T][2] = b.z * SN; biasHN[T][3] = b.w * SN;
        }
    }

    const int t0 = d ? (TT - 1) : 0;
    const int dt = d ? -1 : 1;

    bf16x8 hHi = {};
    float hprev[2][4] = {{0.f,0.f,0.f,0.f},{0.f,0.f,0.f,0.f}};

    // ---- one full GRU step (x regs in, h state updated, store h row) ----
    auto STEP = [&](uint4 xa, uint4 xb, float2 xs, unsigned short* outp) {
        f32x4 acc[6];
        if constexpr (!IS_L0) {
            bf16x8 a0 = __builtin_bit_cast(bf16x8, xa);
            bf16x8 a1 = __builtin_bit_cast(bf16x8, xb);
            #pragma unroll
            for (int t = 0; t < 6; ++t) {
                acc[t] = mfma16(wihF[t][0], a0, biasIn[t]);
                acc[t] = mfma16(wihF[t][1], a1, acc[t]);
            }
        } else {
            #pragma unroll
            for (int t = 0; t < 6; ++t)
                #pragma unroll
                for (int q = 0; q < 4; ++q)
                    acc[t][q] = fmaf(xs.x, w0c[t][q], fmaf(xs.y, w1c[t][q], biasIn[t][q]));
        }

        // ---- recurrence: (whhHi + whhLo) * hHi  (W precise, h bf16) ----
        #pragma unroll
        for (int t = 0; t < 4; ++t) {
            acc[t] = mfma16(whhHi[t], hHi, acc[t]);
            acc[t] = mfma16(whhLo[t], hHi, acc[t]);
        }
        f32x4 accHN[2];
        #pragma unroll
        for (int T = 0; T < 2; ++T) {
            accHN[T] = mfma16(whhHi[4 + T], hHi, biasHN[T]);
            accHN[T] = mfma16(whhLo[4 + T], hHi, accHN[T]);
        }

        unsigned int hw[4];
        #pragma unroll
        for (int T = 0; T < 2; ++T) {
            float h0 = hprev[T][0], h1 = hprev[T][1];
            float h2 = hprev[T][2], h3 = hprev[T][3];
            gate_pair(acc[T][0], acc[T][1], acc[2 + T][0], acc[2 + T][1],
                      acc[4 + T][0], acc[4 + T][1], accHN[T][0], accHN[T][1], h0, h1);
            gate_pair(acc[T][2], acc[T][3], acc[2 + T][2], acc[2 + T][3],
                      acc[4 + T][2], acc[4 + T][3], accHN[T][2], accHN[T][3], h2, h3);
            hprev[T][0] = h0; hprev[T][1] = h1; hprev[T][2] = h2; hprev[T][3] = h3;
            hw[2 * T]     = cvt_pk(h0, h1);
            hw[2 * T + 1] = cvt_pk(h2, h3);
        }
        hHi = __builtin_bit_cast(bf16x8, *(uint4*)hw);
        *(uint4*)outp = *(uint4*)hw;
    };

    // ---- pointers: A = even steps, B = odd steps ----
    const unsigned short* xptrA = nullptr; const unsigned short* xptrB = nullptr;
    const float* xfpA = nullptr; const float* xfpB = nullptr;
    uint4 xA0 = {}, xA1 = {}, xB0 = {}, xB1 = {};
    float2 xsA = {}, xsB = {};
    if constexpr (!IS_L0) {
        xptrA = bin + ((size_t)(b0 + col) * TT + t0) * 64 + qd * 8;
        xptrB = xptrA + dt * 64;
        xA0 = *(const uint4*)xptrA; xA1 = *(const uint4*)(xptrA + 32);
        xB0 = *(const uint4*)xptrB; xB1 = *(const uint4*)(xptrB + 32);
    } else {
        xfpA = x0 + ((size_t)(b0 + col) * TT + t0) * 2;
        xfpB = xfpA + dt * 2;
        xsA = *(const float2*)xfpA;
        xsB = *(const float2*)xfpB;
    }
    unsigned short* optrA = bout + ((size_t)(b0 + col) * TT + t0) * 64 + d * 32 + qd * 8;
    unsigned short* optrB = optrA + dt * 64;

    for (int k = 0; k < 31; ++k) {            // steps 0..61, prefetch 2..63
        STEP(xA0, xA1, xsA, optrA); optrA += dt * 128;
        if constexpr (!IS_L0) {
            xptrA += dt * 128;
            xA0 = *(const uint4*)xptrA; xA1 = *(const uint4*)(xptrA + 32);
        } else {
            xfpA += dt * 4; xsA = *(const float2*)xfpA;
        }
        STEP(xB0, xB1, xsB, optrB); optrB += dt * 128;
        if constexpr (!IS_L0) {
            xptrB += dt * 128;
            xB0 = *(const uint4*)xptrB; xB1 = *(const uint4*)(xptrB + 32);
        } else {
            xfpB += dt * 4; xsB = *(const float2*)xfpB;
        }
    }
    STEP(xA0, xA1, xsA, optrA);               // s = 62
    STEP(xB0, xB1, xsB, optrB);               // s = 63
}

__global__ __launch_bounds__(256)
void fc_kernel(const unsigned short* __restrict__ bin,
               const float* __restrict__ Wfc,
               const float* __restrict__ bfc,
               float* __restrict__ out)
{
    __shared__ float sw[128];
    __shared__ float sb[2];
    const int tid = threadIdx.x;
    if (tid < 128) sw[tid] = Wfc[tid];
    if (tid < 2) sb[tid] = bfc[tid];
    __syncthreads();

    const size_t uidx = (size_t)blockIdx.x * 256 + tid;
    const unsigned short* ip = bin + uidx * 64;
    float a0 = sb[0], a1 = sb[1];
    #pragma unroll
    for (int i = 0; i < 64; i += 8) {
        uint4 raw = *(const uint4*)(ip + i);
        #pragma unroll
        for (int w = 0; w < 4; ++w) {
            unsigned int uu = ((const unsigned int*)&raw)[w];
            float f0 = __uint_as_float(uu << 16);
            float f1 = __uint_as_float(uu & 0xffff0000u);
            a0 = fmaf(f0, sw[i + 2 * w], a0);
            a1 = fmaf(f0, sw[64 + i + 2 * w], a1);
            a0 = fmaf(f1, sw[i + 2 * w + 1], a0);
            a1 = fmaf(f1, sw[64 + i + 2 * w + 1], a1);
        }
    }
    float2 o;
    o.x = tanh_fast(a0);
    o.y = tanh_fast(a1);
    *(float2*)&out[2 * uidx] = o;
}

extern "C" void kernel_launch(void* const* d_in, const int* in_sizes, int n_in,
                              void* d_out, int out_size, void* d_ws, size_t ws_size,
                              hipStream_t stream)
{
    const float* x    = (const float*)d_in[0];
    const float* Wih0 = (const float*)d_in[1];
    const float* Whh0 = (const float*)d_in[2];
    const float* bih0 = (const float*)d_in[3];
    const float* bhh0 = (const float*)d_in[4];
    const float* WihL = (const float*)d_in[5];
    const float* WhhL = (const float*)d_in[6];
    const float* bihL = (const float*)d_in[7];
    const float* bhhL = (const float*)d_in[8];
    const float* Wfc  = (const float*)d_in[9];
    const float* bfc  = (const float*)d_in[10];

    unsigned short* buf0 = (unsigned short*)d_ws;
    unsigned short* buf1 = buf0 + (size_t)BB * TT * 64;
    float* out = (float*)d_out;

    gru_mfma<true><<<512, 256, 0, stream>>>(
        x, nullptr, Wih0, Whh0, bih0, bhh0, buf0);
    gru_mfma<false><<<512, 256, 0, stream>>>(
        nullptr, buf0, WihL, WhhL, bihL, bhhL, buf1);
    gru_mfma<false><<<512, 256, 0, stream>>>(
        nullptr, buf1, WihL + 2 * 96 * 64, WhhL + 2 * 96 * 32,
        bihL + 2 * 96, bhhL + 2 * 96, buf0);
    fc_kernel<<<(BB * TT) / 256, 256, 0, stream>>>(buf0, Wfc, bfc, out);
}